// Round 6
// baseline (1114.979 us; speedup 1.0000x reference)
//
#include <hip/hip_runtime.h>
#include <math.h>

#define B_   8
#define C_   768
#define T_   1024
#define NH_  12
#define DH_  64
#define BT_  (B_*T_)       // 8192
#define WSZ  (C_*C_)       // 589824 per weight matrix

using bf16x8 = __attribute__((ext_vector_type(8))) short;
using f32x4  = __attribute__((ext_vector_type(4))) float;
typedef unsigned short u16;

// ---- bf16 split helpers (round-to-nearest-even) ----
__device__ inline u16 bf16_hi(float x) {
    unsigned u = __builtin_bit_cast(unsigned, x);
    u = (u + 0x7fffu + ((u >> 16) & 1u)) >> 16;
    return (u16)u;
}
__device__ inline float bf16_f(u16 h) {
    unsigned u = ((unsigned)h) << 16;
    return __builtin_bit_cast(float, u);
}
__device__ inline void split_bf16(float x, u16& h, u16& l) {
    h = bf16_hi(x);
    l = bf16_hi(x - bf16_f(h));
}

// ---------------------------------------------------------------------------
// Kernel 0: all 5 weight mats fp32 -> bf16 hi/lo split in one launch.
// ---------------------------------------------------------------------------
__global__ __launch_bounds__(256) void wconv_all(
    const float* __restrict__ W0, const float* __restrict__ W1,
    const float* __restrict__ W2, const float* __restrict__ W3,
    const float* __restrict__ W4, u16* __restrict__ wbuf) {
    int mat = blockIdx.y;
    const float* W = (mat == 0) ? W0 : (mat == 1) ? W1 : (mat == 2) ? W2
                   : (mat == 3) ? W3 : W4;
    u16* hi = wbuf + (size_t)mat * 2 * WSZ;
    u16* lo = hi + WSZ;
    int i = (blockIdx.x * 256 + threadIdx.x) * 4;
    float4 w = *(const float4*)(W + i);
    ushort4 h, l;
    split_bf16(w.x, h.x, l.x);
    split_bf16(w.y, h.y, l.y);
    split_bf16(w.z, h.z, l.z);
    split_bf16(w.w, h.w, l.w);
    *(ushort4*)(hi + i) = h;
    *(ushort4*)(lo + i) = l;
}

// ---------------------------------------------------------------------------
// Kernel 1: LayerNorm with (B,C,T)->(B*T,C) transpose; writes bf16 hi/lo.
// ---------------------------------------------------------------------------
__global__ __launch_bounds__(256) void ln_kernel(const float* __restrict__ x,
                                                 const float* __restrict__ gamma,
                                                 const float* __restrict__ beta,
                                                 u16* __restrict__ xh,
                                                 u16* __restrict__ xl) {
    int row = blockIdx.x;
    int b = row >> 10;
    int t = row & 1023;
    int tid = threadIdx.x;
    const float* xb = x + (size_t)b * C_ * T_ + t;
    float v0 = xb[(size_t)(tid      ) * T_];
    float v1 = xb[(size_t)(tid + 256) * T_];
    float v2 = xb[(size_t)(tid + 512) * T_];
    float s  = v0 + v1 + v2;
    float sq = v0 * v0 + v1 * v1 + v2 * v2;
    #pragma unroll
    for (int m = 1; m < 64; m <<= 1) {
        s  += __shfl_xor(s,  m);
        sq += __shfl_xor(sq, m);
    }
    __shared__ float ss[4], ssq[4];
    int wid = tid >> 6;
    if ((tid & 63) == 0) { ss[wid] = s; ssq[wid] = sq; }
    __syncthreads();
    s  = ss[0] + ss[1] + ss[2] + ss[3];
    sq = ssq[0] + ssq[1] + ssq[2] + ssq[3];
    float mu   = s * (1.0f / 768.0f);
    float var  = sq * (1.0f / 768.0f) - mu * mu;
    float rstd = 1.0f / sqrtf(var + 1e-5f);
    size_t o = (size_t)row * C_;
    float r0 = (v0 - mu) * rstd * gamma[tid      ] + beta[tid      ];
    float r1 = (v1 - mu) * rstd * gamma[tid + 256] + beta[tid + 256];
    float r2 = (v2 - mu) * rstd * gamma[tid + 512] + beta[tid + 512];
    u16 h, l;
    split_bf16(r0, h, l); xh[o + tid      ] = h; xl[o + tid      ] = l;
    split_bf16(r1, h, l); xh[o + tid + 256] = h; xl[o + tid + 256] = l;
    split_bf16(r2, h, l); xh[o + tid + 512] = h; xl[o + tid + 512] = l;
}

// ---------------------------------------------------------------------------
// Kernel 2: fused QKVG GEMM, split-bf16, 16x16x32 MFMA.
// Register double-buffer: tile k+1 loaded to VGPRs while tile k computes.
// Fragment-ordered LDS: block j (512 u16) = one 16x32 fragment, element
// addressing = lane*8 u16 -> stores AND reads are stride-16B conflict-free.
// Staging map: thread t -> block j=t>>5, u=t&31:
//   slot p=u    : row j*16+(u&15), k (u>>4)*8      -> LDS j*512 + u*8
//   slot p=u+32 : same row,        k 16+(u>>4)*8   -> LDS j*512 + 256 + u*8
// mat 0/1: q/k bf16 hi/lo token-major (q pre-scaled 1/8);
// mat 2:   operands swapped -> V^T [b,h,d,t] bf16 hi/lo;
// mat 3:   gate, PLAIN bf16 (hi*hi only, 1 MFMA) -- sigmoid damps the error.
// ---------------------------------------------------------------------------
__global__ __launch_bounds__(256, 3) void qkvg_mfma(
    const u16* __restrict__ xh, const u16* __restrict__ xl,
    const u16* __restrict__ wmats,
    const float* __restrict__ bq, const float* __restrict__ bk,
    const float* __restrict__ bv, const float* __restrict__ bg,
    u16* __restrict__ qh, u16* __restrict__ ql,
    u16* __restrict__ kh, u16* __restrict__ kl,
    u16* __restrict__ vth, u16* __restrict__ vtl,
    u16* __restrict__ g) {
    int bx = blockIdx.x;            // m tile 0..63
    int by = blockIdx.y;            // 0..23
    int mat = by / 6;
    int n0  = (by % 6) * 128;
    int m0  = bx * 128;
    const u16* Wh = wmats + (size_t)mat * 2 * WSZ;
    const u16* Wl = Wh + WSZ;
    const float* bias = (mat == 0) ? bq : (mat == 1) ? bk : (mat == 2) ? bv : bg;
    bool full = (mat != 3);

    __shared__ u16 Ah[4096], Al[4096], Bh[4096], Bl[4096];

    int tid  = threadIdx.x;
    int lane = tid & 63, wid = tid >> 6;
    int wm = (wid & 1) * 64, wn = (wid >> 1) * 64;
    int fr = lane & 15, rq = (lane >> 4) * 4;

    f32x4 acc[4][4];
    #pragma unroll
    for (int i = 0; i < 4; ++i)
        #pragma unroll
        for (int j = 0; j < 4; ++j)
            acc[i][j] = (f32x4){0.f, 0.f, 0.f, 0.f};

    // staging geometry
    int j = tid >> 5, u = tid & 31;
    size_t offA = (size_t)(m0 + j * 16 + (u & 15)) * 768 + (u >> 4) * 8;
    size_t offB = (size_t)(n0 + j * 16 + (u & 15)) * 768 + (u >> 4) * 8;
    int lo0 = j * 512 + u * 8;      // u16 units
    int ba = (wm >> 4), bb2 = (wn >> 4);   // fragment block bases (0 or 4)

    uint4 pa0, pa1, pb0, pb1, pc0, pc1, pd0, pd1;
    #define LOADTILE(K) do { \
        pa0 = *(const uint4*)(xh + offA + (K)); \
        pa1 = *(const uint4*)(xh + offA + (K) + 16); \
        pc0 = *(const uint4*)(Wh + offB + (K)); \
        pc1 = *(const uint4*)(Wh + offB + (K) + 16); \
        if (full) { \
            pb0 = *(const uint4*)(xl + offA + (K)); \
            pb1 = *(const uint4*)(xl + offA + (K) + 16); \
            pd0 = *(const uint4*)(Wl + offB + (K)); \
            pd1 = *(const uint4*)(Wl + offB + (K) + 16); \
        } \
    } while (0)

    LOADTILE(0);
    for (int k0 = 0; k0 < 768; k0 += 32) {
        __syncthreads();            // prior tile's LDS reads complete
        *(uint4*)(Ah + lo0) = pa0;  *(uint4*)(Ah + lo0 + 256) = pa1;
        *(uint4*)(Bh + lo0) = pc0;  *(uint4*)(Bh + lo0 + 256) = pc1;
        if (full) {
            *(uint4*)(Al + lo0) = pb0;  *(uint4*)(Al + lo0 + 256) = pb1;
            *(uint4*)(Bl + lo0) = pd0;  *(uint4*)(Bl + lo0 + 256) = pd1;
        }
        __syncthreads();            // staged and visible
        if (k0 + 32 < 768) LOADTILE(k0 + 32);   // prefetch overlaps MFMAs
        bf16x8 fah[4], fal[4], fbh[4], fbl[4];
        #pragma unroll
        for (int i = 0; i < 4; ++i) {
            fah[i] = *(const bf16x8*)(Ah + (ba + i) * 512 + lane * 8);
            fbh[i] = *(const bf16x8*)(Bh + (bb2 + i) * 512 + lane * 8);
            if (full) {
                fal[i] = *(const bf16x8*)(Al + (ba + i) * 512 + lane * 8);
                fbl[i] = *(const bf16x8*)(Bl + (bb2 + i) * 512 + lane * 8);
            }
        }
        if (mat == 2) {
            #pragma unroll
            for (int mi = 0; mi < 4; ++mi)
                #pragma unroll
                for (int ni = 0; ni < 4; ++ni) {
                    acc[mi][ni] = __builtin_amdgcn_mfma_f32_16x16x32_bf16(fbh[ni], fah[mi], acc[mi][ni], 0, 0, 0);
                    acc[mi][ni] = __builtin_amdgcn_mfma_f32_16x16x32_bf16(fbh[ni], fal[mi], acc[mi][ni], 0, 0, 0);
                    acc[mi][ni] = __builtin_amdgcn_mfma_f32_16x16x32_bf16(fbl[ni], fah[mi], acc[mi][ni], 0, 0, 0);
                }
        } else if (full) {
            #pragma unroll
            for (int mi = 0; mi < 4; ++mi)
                #pragma unroll
                for (int ni = 0; ni < 4; ++ni) {
                    acc[mi][ni] = __builtin_amdgcn_mfma_f32_16x16x32_bf16(fah[mi], fbh[ni], acc[mi][ni], 0, 0, 0);
                    acc[mi][ni] = __builtin_amdgcn_mfma_f32_16x16x32_bf16(fah[mi], fbl[ni], acc[mi][ni], 0, 0, 0);
                    acc[mi][ni] = __builtin_amdgcn_mfma_f32_16x16x32_bf16(fal[mi], fbh[ni], acc[mi][ni], 0, 0, 0);
                }
        } else {   // gate: plain bf16
            #pragma unroll
            for (int mi = 0; mi < 4; ++mi)
                #pragma unroll
                for (int ni = 0; ni < 4; ++ni)
                    acc[mi][ni] = __builtin_amdgcn_mfma_f32_16x16x32_bf16(fah[mi], fbh[ni], acc[mi][ni], 0, 0, 0);
        }
    }
    #undef LOADTILE
    // epilogue: C/D layout col=lane&15, row=(lane>>4)*4+reg
    if (mat == 2) {
        int bb = m0 >> 10;
        #pragma unroll
        for (int mi = 0; mi < 4; ++mi) {
            int tok = m0 + wm + mi * 16 + fr;
            int tl  = tok & 1023;
            #pragma unroll
            for (int ni = 0; ni < 4; ++ni) {
                #pragma unroll
                for (int rg = 0; rg < 4; ++rg) {
                    int ch = n0 + wn + ni * 16 + rq + rg;
                    float val = acc[mi][ni][rg] + bias[ch];
                    size_t addr = ((size_t)((bb * 12 + (ch >> 6)) * 64 + (ch & 63))) * 1024 + tl;
                    u16 h, l;
                    split_bf16(val, h, l);
                    vth[addr] = h;
                    vtl[addr] = l;
                }
            }
        }
    } else {
        u16* oh = (mat == 0) ? qh : (mat == 1) ? kh : g;
        u16* ol = (mat == 0) ? ql : kl;
        #pragma unroll
        for (int ni = 0; ni < 4; ++ni) {
            int col = n0 + wn + ni * 16 + fr;
            float bb = bias[col];
            #pragma unroll
            for (int mi = 0; mi < 4; ++mi) {
                int row = m0 + wm + mi * 16 + rq;
                #pragma unroll
                for (int rg = 0; rg < 4; ++rg) {
                    float val = acc[mi][ni][rg] + bb;
                    size_t addr = (size_t)(row + rg) * 768 + col;
                    if (mat == 3) {
                        g[addr] = bf16_hi(val);
                    } else {
                        if (mat == 0) val *= 0.125f;
                        u16 h, l;
                        split_bf16(val, h, l);
                        oh[addr] = h;
                        ol[addr] = l;
                    }
                }
            }
        }
    }
}

// ---------------------------------------------------------------------------
// Kernel 3: MFMA flash attention (16x16x32) + bf16 sigmoid gate.
// Register double-buffer of K/V tiles; fragment-ordered LDS (conflict-free);
// 2 barriers per KV stage; P via wave-private LDS strip (no barrier).
// ---------------------------------------------------------------------------
__global__ __launch_bounds__(256, 3) void attn_mfma(
    const u16* __restrict__ qhg, const u16* __restrict__ qlg,
    const u16* __restrict__ khg, const u16* __restrict__ klg,
    const u16* __restrict__ vthg, const u16* __restrict__ vtlg,
    const u16* __restrict__ gbf,
    u16* __restrict__ yh, u16* __restrict__ yl) {
    int qt = blockIdx.x;   // 0..15
    int h  = blockIdx.y;   // 0..11
    int b  = blockIdx.z;   // 0..7
    __shared__ u16 Kh[4096], Kl[4096], Vh[4096], Vl[4096];
    __shared__ u16 Ps[64 * 72];
    int tid = threadIdx.x;
    int lane = tid & 63, w = tid >> 6;
    int fr = lane & 15, quad = lane >> 4, fq = quad * 8;

    size_t qbase = ((size_t)(b * 1024 + qt * 64)) * 768 + h * 64;
    size_t kbase = ((size_t)(b * 1024)) * 768 + h * 64;
    size_t vbase = ((size_t)((b * 12 + h) * 64)) * 1024;

    // Q A-fragments direct from global (loop-invariant)
    bf16x8 aqh[2], aql[2];
    #pragma unroll
    for (int kk = 0; kk < 2; ++kk) {
        size_t off = qbase + (size_t)(w * 16 + fr) * 768 + kk * 32 + fq;
        aqh[kk] = *(const bf16x8*)(qhg + off);
        aql[kk] = *(const bf16x8*)(qlg + off);
    }
    float m_i[4], l_i[4];
    f32x4 Oacc[4];
    #pragma unroll
    for (int i = 0; i < 4; ++i) {
        m_i[i] = -1e30f; l_i[i] = 0.0f;
        Oacc[i] = (f32x4){0.f, 0.f, 0.f, 0.f};
    }

    // staging geometry: block j=t>>5 (K: kk=j>>2,nt=j&3; V: kk=j>>2,dn=j&3)
    int j = tid >> 5, u = tid & 31;
    int kk_ = j >> 2, nd_ = j & 3;
    size_t offK = kbase + (size_t)(nd_ * 16 + (u & 15)) * 768 + kk_ * 32 + (u >> 4) * 8;
    size_t offV = vbase + (size_t)(nd_ * 16 + (u & 15)) * 1024 + kk_ * 32 + (u >> 4) * 8;
    int lo0 = j * 512 + u * 8;

    uint4 rk0, rk1, rl0, rl1, rv0, rv1, rw0, rw1;
    #define LOADKV(ST) do { \
        size_t ok = offK + (size_t)(ST) * 49152; \
        size_t ov = offV + (size_t)(ST) * 64; \
        rk0 = *(const uint4*)(khg + ok);  rk1 = *(const uint4*)(khg + ok + 16); \
        rl0 = *(const uint4*)(klg + ok);  rl1 = *(const uint4*)(klg + ok + 16); \
        rv0 = *(const uint4*)(vthg + ov); rv1 = *(const uint4*)(vthg + ov + 16); \
        rw0 = *(const uint4*)(vtlg + ov); rw1 = *(const uint4*)(vtlg + ov + 16); \
    } while (0)

    LOADKV(0);
    for (int st = 0; st < 16; ++st) {
        __syncthreads();            // prior stage's K/V reads complete
        *(uint4*)(Kh + lo0) = rk0;  *(uint4*)(Kh + lo0 + 256) = rk1;
        *(uint4*)(Kl + lo0) = rl0;  *(uint4*)(Kl + lo0 + 256) = rl1;
        *(uint4*)(Vh + lo0) = rv0;  *(uint4*)(Vh + lo0 + 256) = rv1;
        *(uint4*)(Vl + lo0) = rw0;  *(uint4*)(Vl + lo0 + 256) = rw1;
        __syncthreads();            // staged and visible
        if (st < 15) LOADKV(st + 1);   // prefetch overlaps compute
        // S = Q K^T (wave strip 16 x 64), 3-MFMA split
        f32x4 sacc[4];
        #pragma unroll
        for (int nt = 0; nt < 4; ++nt) sacc[nt] = (f32x4){0.f, 0.f, 0.f, 0.f};
        #pragma unroll
        for (int nt = 0; nt < 4; ++nt)
            #pragma unroll
            for (int kk = 0; kk < 2; ++kk) {
                bf16x8 kbh = *(const bf16x8*)(Kh + (kk * 4 + nt) * 512 + lane * 8);
                bf16x8 kbl = *(const bf16x8*)(Kl + (kk * 4 + nt) * 512 + lane * 8);
                sacc[nt] = __builtin_amdgcn_mfma_f32_16x16x32_bf16(aqh[kk], kbh, sacc[nt], 0, 0, 0);
                sacc[nt] = __builtin_amdgcn_mfma_f32_16x16x32_bf16(aqh[kk], kbl, sacc[nt], 0, 0, 0);
                sacc[nt] = __builtin_amdgcn_mfma_f32_16x16x32_bf16(aql[kk], kbh, sacc[nt], 0, 0, 0);
            }
        // online softmax per owned row (row = w*16 + quad*4 + rg)
        #pragma unroll
        for (int rg = 0; rg < 4; ++rg) {
            float mx = fmaxf(fmaxf(sacc[0][rg], sacc[1][rg]),
                             fmaxf(sacc[2][rg], sacc[3][rg]));
            #pragma unroll
            for (int msk = 1; msk < 16; msk <<= 1) mx = fmaxf(mx, __shfl_xor(mx, msk));
            float mn = fmaxf(m_i[rg], mx);
            float al = __expf(m_i[rg] - mn);
            float p0 = __expf(sacc[0][rg] - mn);
            float p1 = __expf(sacc[1][rg] - mn);
            float p2 = __expf(sacc[2][rg] - mn);
            float p3 = __expf(sacc[3][rg] - mn);
            float rs = p0 + p1 + p2 + p3;
            #pragma unroll
            for (int msk = 1; msk < 16; msk <<= 1) rs += __shfl_xor(rs, msk);
            l_i[rg] = l_i[rg] * al + rs;
            m_i[rg] = mn;
            #pragma unroll
            for (int dn = 0; dn < 4; ++dn) Oacc[dn][rg] *= al;
            int row = w * 16 + quad * 4 + rg;
            Ps[row * 72 +  0 + fr] = bf16_hi(p0);
            Ps[row * 72 + 16 + fr] = bf16_hi(p1);
            Ps[row * 72 + 32 + fr] = bf16_hi(p2);
            Ps[row * 72 + 48 + fr] = bf16_hi(p3);
        }
        // O += P V (P wave-private; V staged this stage)
        #pragma unroll
        for (int kk = 0; kk < 2; ++kk) {
            bf16x8 pa = *(const bf16x8*)&Ps[(w * 16 + fr) * 72 + fq + kk * 32];
            #pragma unroll
            for (int dn = 0; dn < 4; ++dn) {
                bf16x8 vbh = *(const bf16x8*)(Vh + (kk * 4 + dn) * 512 + lane * 8);
                bf16x8 vbl = *(const bf16x8*)(Vl + (kk * 4 + dn) * 512 + lane * 8);
                Oacc[dn] = __builtin_amdgcn_mfma_f32_16x16x32_bf16(pa, vbh, Oacc[dn], 0, 0, 0);
                Oacc[dn] = __builtin_amdgcn_mfma_f32_16x16x32_bf16(pa, vbl, Oacc[dn], 0, 0, 0);
            }
        }
    }
    #undef LOADKV
    // epilogue: normalize, sigmoid gate, split-store y
    float inv[4];
    #pragma unroll
    for (int rg = 0; rg < 4; ++rg) inv[rg] = 1.0f / l_i[rg];
    #pragma unroll
    for (int dn = 0; dn < 4; ++dn) {
        int ch = h * 64 + dn * 16 + fr;
        #pragma unroll
        for (int rg = 0; rg < 4; ++rg) {
            int tok = b * 1024 + qt * 64 + w * 16 + quad * 4 + rg;
            float gv = bf16_f(gbf[(size_t)tok * 768 + ch]);
            float sg = 1.0f / (1.0f + __expf(-gv));
            float val = Oacc[dn][rg] * inv[rg] * sg;
            u16 hh, ll;
            split_bf16(val, hh, ll);
            yh[(size_t)tok * 768 + ch] = hh;
            yl[(size_t)tok * 768 + ch] = ll;
        }
    }
}

// ---------------------------------------------------------------------------
// Kernel 4: out = y @ Wo^T + bo -> (B, C, T), split-bf16 16x16x32 MFMA,
// same register-double-buffer + fragment-ordered-LDS structure as qkvg.
// ---------------------------------------------------------------------------
__global__ __launch_bounds__(256, 3) void out_mfma(
    const u16* __restrict__ yh, const u16* __restrict__ yl,
    const u16* __restrict__ woh, const u16* __restrict__ wol,
    const float* __restrict__ bo, float* __restrict__ out) {
    int bx = blockIdx.x;   // c tile 0..5
    int by = blockIdx.y;   // t tile 0..63
    int m0 = bx * 128;     // c
    int n0 = by * 128;     // t

    __shared__ u16 Ah[4096], Al[4096], Bh[4096], Bl[4096];

    int tid  = threadIdx.x;
    int lane = tid & 63, wid = tid >> 6;
    int wm = (wid & 1) * 64, wn = (wid >> 1) * 64;
    int fr = lane & 15, rq = (lane >> 4) * 4;

    f32x4 acc[4][4];
    #pragma unroll
    for (int i = 0; i < 4; ++i)
        #pragma unroll
        for (int j = 0; j < 4; ++j)
            acc[i][j] = (f32x4){0.f, 0.f, 0.f, 0.f};

    int j = tid >> 5, u = tid & 31;
    size_t offA = (size_t)(m0 + j * 16 + (u & 15)) * 768 + (u >> 4) * 8;
    size_t offB = (size_t)(n0 + j * 16 + (u & 15)) * 768 + (u >> 4) * 8;
    int lo0 = j * 512 + u * 8;
    int ba = (wm >> 4), bb2 = (wn >> 4);

    uint4 pa0, pa1, pb0, pb1, pc0, pc1, pd0, pd1;
    #define LOADTILE(K) do { \
        pa0 = *(const uint4*)(woh + offA + (K)); \
        pa1 = *(const uint4*)(woh + offA + (K) + 16); \
        pb0 = *(const uint4*)(wol + offA + (K)); \
        pb1 = *(const uint4*)(wol + offA + (K) + 16); \
        pc0 = *(const uint4*)(yh + offB + (K)); \
        pc1 = *(const uint4*)(yh + offB + (K) + 16); \
        pd0 = *(const uint4*)(yl + offB + (K)); \
        pd1 = *(const uint4*)(yl + offB + (K) + 16); \
    } while (0)

    LOADTILE(0);
    for (int k0 = 0; k0 < 768; k0 += 32) {
        __syncthreads();
        *(uint4*)(Ah + lo0) = pa0;  *(uint4*)(Ah + lo0 + 256) = pa1;
        *(uint4*)(Al + lo0) = pb0;  *(uint4*)(Al + lo0 + 256) = pb1;
        *(uint4*)(Bh + lo0) = pc0;  *(uint4*)(Bh + lo0 + 256) = pc1;
        *(uint4*)(Bl + lo0) = pd0;  *(uint4*)(Bl + lo0 + 256) = pd1;
        __syncthreads();
        if (k0 + 32 < 768) LOADTILE(k0 + 32);
        bf16x8 fah[4], fal[4], fbh[4], fbl[4];
        #pragma unroll
        for (int i = 0; i < 4; ++i) {
            fah[i] = *(const bf16x8*)(Ah + (ba + i) * 512 + lane * 8);
            fal[i] = *(const bf16x8*)(Al + (ba + i) * 512 + lane * 8);
            fbh[i] = *(const bf16x8*)(Bh + (bb2 + i) * 512 + lane * 8);
            fbl[i] = *(const bf16x8*)(Bl + (bb2 + i) * 512 + lane * 8);
        }
        #pragma unroll
        for (int mi = 0; mi < 4; ++mi)
            #pragma unroll
            for (int ni = 0; ni < 4; ++ni) {
                acc[mi][ni] = __builtin_amdgcn_mfma_f32_16x16x32_bf16(fah[mi], fbh[ni], acc[mi][ni], 0, 0, 0);
                acc[mi][ni] = __builtin_amdgcn_mfma_f32_16x16x32_bf16(fah[mi], fbl[ni], acc[mi][ni], 0, 0, 0);
                acc[mi][ni] = __builtin_amdgcn_mfma_f32_16x16x32_bf16(fal[mi], fbh[ni], acc[mi][ni], 0, 0, 0);
            }
    }
    #undef LOADTILE
    int bb = n0 >> 10;
    #pragma unroll
    for (int ni = 0; ni < 4; ++ni) {
        int colg = n0 + wn + ni * 16 + fr;
        int tl = colg & 1023;
        #pragma unroll
        for (int mi = 0; mi < 4; ++mi) {
            int row = m0 + wm + mi * 16 + rq;
            #pragma unroll
            for (int rg = 0; rg < 4; ++rg) {
                float val = acc[mi][ni][rg] + bo[row + rg];
                out[((size_t)bb * 768 + row + rg) * 1024 + tl] = val;
            }
        }
    }
}

extern "C" void kernel_launch(void* const* d_in, const int* in_sizes, int n_in,
                              void* d_out, int out_size, void* d_ws, size_t ws_size,
                              hipStream_t stream) {
    const float* x     = (const float*)d_in[0];
    const float* Wq    = (const float*)d_in[1];
    const float* bq    = (const float*)d_in[2];
    const float* Wk    = (const float*)d_in[3];
    const float* bk    = (const float*)d_in[4];
    const float* Wv    = (const float*)d_in[5];
    const float* bv    = (const float*)d_in[6];
    const float* Wo    = (const float*)d_in[7];
    const float* bo    = (const float*)d_in[8];
    const float* Wg    = (const float*)d_in[9];
    const float* bg    = (const float*)d_in[10];
    const float* gamma = (const float*)d_in[11];
    const float* beta  = (const float*)d_in[12];
    float* out = (float*)d_out;

    // workspace (ushort): xn_h|xn_l|qh|ql|kh|kl|vth|vtl|g | wbuf
    const size_t S = (size_t)BT_ * C_;
    u16* xn_hi = (u16*)d_ws;
    u16* xn_lo = xn_hi + S;
    u16* qh    = xn_lo + S;
    u16* ql    = qh + S;
    u16* kh    = ql + S;
    u16* kl    = kh + S;
    u16* vth   = kl + S;
    u16* vtl   = vth + S;
    u16* g_bf  = vtl + S;
    u16* wbuf  = g_bf + S;   // [Wq,Wk,Wv,Wg,Wo] x {hi,lo}
    u16* y_hi  = xn_hi;      // alias: xn dead after qkvg
    u16* y_lo  = xn_lo;

    wconv_all<<<dim3(WSZ / 1024, 5), 256, 0, stream>>>(Wq, Wk, Wv, Wg, Wo, wbuf);
    ln_kernel<<<BT_, 256, 0, stream>>>(x, gamma, beta, xn_hi, xn_lo);
    qkvg_mfma<<<dim3(64, 24), 256, 0, stream>>>(xn_hi, xn_lo, wbuf,
                                                bq, bk, bv, bg,
                                                qh, ql, kh, kl, vth, vtl, g_bf);
    attn_mfma<<<dim3(16, 12, 8), 256, 0, stream>>>(qh, ql, kh, kl, vth, vtl,
                                                   g_bf, y_hi, y_lo);
    out_mfma<<<dim3(6, 64), 256, 0, stream>>>(y_hi, y_lo,
                                              wbuf + (size_t)8 * WSZ,
                                              wbuf + (size_t)9 * WSZ, bo, out);
}

// Round 7
// 462.487 us; speedup vs baseline: 2.4108x; 2.4108x over previous
//
#include <hip/hip_runtime.h>
#include <math.h>

#define B_   8
#define C_   768
#define T_   1024
#define NH_  12
#define DH_  64
#define BT_  (B_*T_)       // 8192
#define WSZ  (C_*C_)       // 589824 per weight matrix

using bf16x8 = __attribute__((ext_vector_type(8))) short;
using f32x4  = __attribute__((ext_vector_type(4))) float;
typedef unsigned short u16;

// ---- bf16 split helpers (round-to-nearest-even) ----
__device__ inline u16 bf16_hi(float x) {
    unsigned u = __builtin_bit_cast(unsigned, x);
    u = (u + 0x7fffu + ((u >> 16) & 1u)) >> 16;
    return (u16)u;
}
__device__ inline float bf16_f(u16 h) {
    unsigned u = ((unsigned)h) << 16;
    return __builtin_bit_cast(float, u);
}
__device__ inline void split_bf16(float x, u16& h, u16& l) {
    h = bf16_hi(x);
    l = bf16_hi(x - bf16_f(h));
}

// ---------------------------------------------------------------------------
// Kernel 0: all 5 weight mats fp32 -> bf16 hi/lo split in one launch.
// ---------------------------------------------------------------------------
__global__ __launch_bounds__(256) void wconv_all(
    const float* __restrict__ W0, const float* __restrict__ W1,
    const float* __restrict__ W2, const float* __restrict__ W3,
    const float* __restrict__ W4, u16* __restrict__ wbuf) {
    int mat = blockIdx.y;
    const float* W = (mat == 0) ? W0 : (mat == 1) ? W1 : (mat == 2) ? W2
                   : (mat == 3) ? W3 : W4;
    u16* hi = wbuf + (size_t)mat * 2 * WSZ;
    u16* lo = hi + WSZ;
    int i = (blockIdx.x * 256 + threadIdx.x) * 4;
    float4 w = *(const float4*)(W + i);
    ushort4 h, l;
    split_bf16(w.x, h.x, l.x);
    split_bf16(w.y, h.y, l.y);
    split_bf16(w.z, h.z, l.z);
    split_bf16(w.w, h.w, l.w);
    *(ushort4*)(hi + i) = h;
    *(ushort4*)(lo + i) = l;
}

// ---------------------------------------------------------------------------
// Kernel 1: LayerNorm with (B,C,T)->(B*T,C) transpose; writes bf16 hi/lo.
// ---------------------------------------------------------------------------
__global__ __launch_bounds__(256) void ln_kernel(const float* __restrict__ x,
                                                 const float* __restrict__ gamma,
                                                 const float* __restrict__ beta,
                                                 u16* __restrict__ xh,
                                                 u16* __restrict__ xl) {
    int row = blockIdx.x;
    int b = row >> 10;
    int t = row & 1023;
    int tid = threadIdx.x;
    const float* xb = x + (size_t)b * C_ * T_ + t;
    float v0 = xb[(size_t)(tid      ) * T_];
    float v1 = xb[(size_t)(tid + 256) * T_];
    float v2 = xb[(size_t)(tid + 512) * T_];
    float s  = v0 + v1 + v2;
    float sq = v0 * v0 + v1 * v1 + v2 * v2;
    #pragma unroll
    for (int m = 1; m < 64; m <<= 1) {
        s  += __shfl_xor(s,  m);
        sq += __shfl_xor(sq, m);
    }
    __shared__ float ss[4], ssq[4];
    int wid = tid >> 6;
    if ((tid & 63) == 0) { ss[wid] = s; ssq[wid] = sq; }
    __syncthreads();
    s  = ss[0] + ss[1] + ss[2] + ss[3];
    sq = ssq[0] + ssq[1] + ssq[2] + ssq[3];
    float mu   = s * (1.0f / 768.0f);
    float var  = sq * (1.0f / 768.0f) - mu * mu;
    float rstd = 1.0f / sqrtf(var + 1e-5f);
    size_t o = (size_t)row * C_;
    float r0 = (v0 - mu) * rstd * gamma[tid      ] + beta[tid      ];
    float r1 = (v1 - mu) * rstd * gamma[tid + 256] + beta[tid + 256];
    float r2 = (v2 - mu) * rstd * gamma[tid + 512] + beta[tid + 512];
    u16 h, l;
    split_bf16(r0, h, l); xh[o + tid      ] = h; xl[o + tid      ] = l;
    split_bf16(r1, h, l); xh[o + tid + 256] = h; xl[o + tid + 256] = l;
    split_bf16(r2, h, l); xh[o + tid + 512] = h; xl[o + tid + 512] = l;
}

// ---------------------------------------------------------------------------
// Kernel 2: fused QKVG GEMM, split-bf16, 16x16x32 MFMA.
// Register double-buffer with UNCONDITIONAL prefetch (conditional prefetch
// assignment spilled to scratch in R6: WRITE_SIZE 2.4 GB, VGPR 84).
// Fragment-ordered LDS: block j (512 u16) = one 16x32 fragment; stores and
// reads both stride-16B -> conflict-free.
// mat 0/1: q/k bf16 hi/lo token-major (q pre-scaled 1/8);
// mat 2:   operands swapped -> V^T [b,h,d,t] bf16 hi/lo;
// mat 3:   gate, plain bf16 (hi*hi only, 1 MFMA).
// ---------------------------------------------------------------------------
__global__ __launch_bounds__(256, 2) void qkvg_mfma(
    const u16* __restrict__ xh, const u16* __restrict__ xl,
    const u16* __restrict__ wmats,
    const float* __restrict__ bq, const float* __restrict__ bk,
    const float* __restrict__ bv, const float* __restrict__ bg,
    u16* __restrict__ qh, u16* __restrict__ ql,
    u16* __restrict__ kh, u16* __restrict__ kl,
    u16* __restrict__ vth, u16* __restrict__ vtl,
    u16* __restrict__ g) {
    int bx = blockIdx.x;            // m tile 0..63
    int by = blockIdx.y;            // 0..23
    int mat = by / 6;
    int n0  = (by % 6) * 128;
    int m0  = bx * 128;
    const u16* Wh = wmats + (size_t)mat * 2 * WSZ;
    const u16* Wl = Wh + WSZ;
    const float* bias = (mat == 0) ? bq : (mat == 1) ? bk : (mat == 2) ? bv : bg;

    __shared__ u16 Ah[4096], Al[4096], Bh[4096], Bl[4096];

    int tid  = threadIdx.x;
    int lane = tid & 63, wid = tid >> 6;
    int wm = (wid & 1) * 64, wn = (wid >> 1) * 64;
    int fr = lane & 15, rq = (lane >> 4) * 4;

    f32x4 acc[4][4];
    #pragma unroll
    for (int i = 0; i < 4; ++i)
        #pragma unroll
        for (int j = 0; j < 4; ++j)
            acc[i][j] = (f32x4){0.f, 0.f, 0.f, 0.f};

    // staging geometry
    int j = tid >> 5, u = tid & 31;
    size_t offA = (size_t)(m0 + j * 16 + (u & 15)) * 768 + (u >> 4) * 8;
    size_t offB = (size_t)(n0 + j * 16 + (u & 15)) * 768 + (u >> 4) * 8;
    int lo0 = j * 512 + u * 8;      // u16 units
    int ba = (wm >> 4), bb2 = (wn >> 4);   // fragment block bases (0 or 4)

    uint4 pa0, pa1, pb0, pb1, pc0, pc1, pd0, pd1;
    #define LOADTILE(K) do { \
        pa0 = *(const uint4*)(xh + offA + (K)); \
        pa1 = *(const uint4*)(xh + offA + (K) + 16); \
        pb0 = *(const uint4*)(xl + offA + (K)); \
        pb1 = *(const uint4*)(xl + offA + (K) + 16); \
        pc0 = *(const uint4*)(Wh + offB + (K)); \
        pc1 = *(const uint4*)(Wh + offB + (K) + 16); \
        pd0 = *(const uint4*)(Wl + offB + (K)); \
        pd1 = *(const uint4*)(Wl + offB + (K) + 16); \
    } while (0)

    LOADTILE(0);
    for (int k0 = 0; k0 < 768; k0 += 32) {
        __syncthreads();            // prior tile's LDS reads complete
        *(uint4*)(Ah + lo0) = pa0;  *(uint4*)(Ah + lo0 + 256) = pa1;
        *(uint4*)(Al + lo0) = pb0;  *(uint4*)(Al + lo0 + 256) = pb1;
        *(uint4*)(Bh + lo0) = pc0;  *(uint4*)(Bh + lo0 + 256) = pc1;
        *(uint4*)(Bl + lo0) = pd0;  *(uint4*)(Bl + lo0 + 256) = pd1;
        __syncthreads();            // staged and visible
        if (k0 + 32 < 768) LOADTILE(k0 + 32);   // prefetch overlaps MFMAs
        bf16x8 fah[4], fal[4], fbh[4], fbl[4];
        #pragma unroll
        for (int i = 0; i < 4; ++i) {
            fah[i] = *(const bf16x8*)(Ah + (ba + i) * 512 + lane * 8);
            fal[i] = *(const bf16x8*)(Al + (ba + i) * 512 + lane * 8);
            fbh[i] = *(const bf16x8*)(Bh + (bb2 + i) * 512 + lane * 8);
            fbl[i] = *(const bf16x8*)(Bl + (bb2 + i) * 512 + lane * 8);
        }
        if (mat == 2) {
            #pragma unroll
            for (int mi = 0; mi < 4; ++mi)
                #pragma unroll
                for (int ni = 0; ni < 4; ++ni) {
                    acc[mi][ni] = __builtin_amdgcn_mfma_f32_16x16x32_bf16(fbh[ni], fah[mi], acc[mi][ni], 0, 0, 0);
                    acc[mi][ni] = __builtin_amdgcn_mfma_f32_16x16x32_bf16(fbh[ni], fal[mi], acc[mi][ni], 0, 0, 0);
                    acc[mi][ni] = __builtin_amdgcn_mfma_f32_16x16x32_bf16(fbl[ni], fah[mi], acc[mi][ni], 0, 0, 0);
                }
        } else if (mat != 3) {
            #pragma unroll
            for (int mi = 0; mi < 4; ++mi)
                #pragma unroll
                for (int ni = 0; ni < 4; ++ni) {
                    acc[mi][ni] = __builtin_amdgcn_mfma_f32_16x16x32_bf16(fah[mi], fbh[ni], acc[mi][ni], 0, 0, 0);
                    acc[mi][ni] = __builtin_amdgcn_mfma_f32_16x16x32_bf16(fah[mi], fbl[ni], acc[mi][ni], 0, 0, 0);
                    acc[mi][ni] = __builtin_amdgcn_mfma_f32_16x16x32_bf16(fal[mi], fbh[ni], acc[mi][ni], 0, 0, 0);
                }
        } else {   // gate: plain bf16
            #pragma unroll
            for (int mi = 0; mi < 4; ++mi)
                #pragma unroll
                for (int ni = 0; ni < 4; ++ni)
                    acc[mi][ni] = __builtin_amdgcn_mfma_f32_16x16x32_bf16(fah[mi], fbh[ni], acc[mi][ni], 0, 0, 0);
        }
    }
    #undef LOADTILE
    // epilogue: C/D layout col=lane&15, row=(lane>>4)*4+reg
    if (mat == 2) {
        int bb = m0 >> 10;
        #pragma unroll
        for (int mi = 0; mi < 4; ++mi) {
            int tok = m0 + wm + mi * 16 + fr;
            int tl  = tok & 1023;
            #pragma unroll
            for (int ni = 0; ni < 4; ++ni) {
                #pragma unroll
                for (int rg = 0; rg < 4; ++rg) {
                    int ch = n0 + wn + ni * 16 + rq + rg;
                    float val = acc[mi][ni][rg] + bias[ch];
                    size_t addr = ((size_t)((bb * 12 + (ch >> 6)) * 64 + (ch & 63))) * 1024 + tl;
                    u16 h, l;
                    split_bf16(val, h, l);
                    vth[addr] = h;
                    vtl[addr] = l;
                }
            }
        }
    } else {
        u16* oh = (mat == 0) ? qh : (mat == 1) ? kh : g;
        u16* ol = (mat == 0) ? ql : kl;
        #pragma unroll
        for (int ni = 0; ni < 4; ++ni) {
            int col = n0 + wn + ni * 16 + fr;
            float bb = bias[col];
            #pragma unroll
            for (int mi = 0; mi < 4; ++mi) {
                int row = m0 + wm + mi * 16 + rq;
                #pragma unroll
                for (int rg = 0; rg < 4; ++rg) {
                    float val = acc[mi][ni][rg] + bb;
                    size_t addr = (size_t)(row + rg) * 768 + col;
                    if (mat == 3) {
                        g[addr] = bf16_hi(val);
                    } else {
                        if (mat == 0) val *= 0.125f;
                        u16 h, l;
                        split_bf16(val, h, l);
                        oh[addr] = h;
                        ol[addr] = l;
                    }
                }
            }
        }
    }
}

// ---------------------------------------------------------------------------
// Kernel 3: MFMA flash attention (16x16x32) + bf16 sigmoid gate.
// Register double-buffer of K/V tiles; fragment-ordered LDS (conflict-free);
// 2 barriers per KV stage; P via wave-private LDS strip (no barrier).
// ---------------------------------------------------------------------------
__global__ __launch_bounds__(256, 3) void attn_mfma(
    const u16* __restrict__ qhg, const u16* __restrict__ qlg,
    const u16* __restrict__ khg, const u16* __restrict__ klg,
    const u16* __restrict__ vthg, const u16* __restrict__ vtlg,
    const u16* __restrict__ gbf,
    u16* __restrict__ yh, u16* __restrict__ yl) {
    int qt = blockIdx.x;   // 0..15
    int h  = blockIdx.y;   // 0..11
    int b  = blockIdx.z;   // 0..7
    __shared__ u16 Kh[4096], Kl[4096], Vh[4096], Vl[4096];
    __shared__ u16 Ps[64 * 72];
    int tid = threadIdx.x;
    int lane = tid & 63, w = tid >> 6;
    int fr = lane & 15, quad = lane >> 4, fq = quad * 8;

    size_t qbase = ((size_t)(b * 1024 + qt * 64)) * 768 + h * 64;
    size_t kbase = ((size_t)(b * 1024)) * 768 + h * 64;
    size_t vbase = ((size_t)((b * 12 + h) * 64)) * 1024;

    // Q A-fragments direct from global (loop-invariant)
    bf16x8 aqh[2], aql[2];
    #pragma unroll
    for (int kk = 0; kk < 2; ++kk) {
        size_t off = qbase + (size_t)(w * 16 + fr) * 768 + kk * 32 + fq;
        aqh[kk] = *(const bf16x8*)(qhg + off);
        aql[kk] = *(const bf16x8*)(qlg + off);
    }
    float m_i[4], l_i[4];
    f32x4 Oacc[4];
    #pragma unroll
    for (int i = 0; i < 4; ++i) {
        m_i[i] = -1e30f; l_i[i] = 0.0f;
        Oacc[i] = (f32x4){0.f, 0.f, 0.f, 0.f};
    }

    // staging geometry: block j=t>>5 (K: kk=j>>2,nt=j&3; V: kk=j>>2,dn=j&3)
    int j = tid >> 5, u = tid & 31;
    int kk_ = j >> 2, nd_ = j & 3;
    size_t offK = kbase + (size_t)(nd_ * 16 + (u & 15)) * 768 + kk_ * 32 + (u >> 4) * 8;
    size_t offV = vbase + (size_t)(nd_ * 16 + (u & 15)) * 1024 + kk_ * 32 + (u >> 4) * 8;
    int lo0 = j * 512 + u * 8;

    uint4 rk0, rk1, rl0, rl1, rv0, rv1, rw0, rw1;
    #define LOADKV(ST) do { \
        size_t ok = offK + (size_t)(ST) * 49152; \
        size_t ov = offV + (size_t)(ST) * 64; \
        rk0 = *(const uint4*)(khg + ok);  rk1 = *(const uint4*)(khg + ok + 16); \
        rl0 = *(const uint4*)(klg + ok);  rl1 = *(const uint4*)(klg + ok + 16); \
        rv0 = *(const uint4*)(vthg + ov); rv1 = *(const uint4*)(vthg + ov + 16); \
        rw0 = *(const uint4*)(vtlg + ov); rw1 = *(const uint4*)(vtlg + ov + 16); \
    } while (0)

    LOADKV(0);
    for (int st = 0; st < 16; ++st) {
        __syncthreads();            // prior stage's K/V reads complete
        *(uint4*)(Kh + lo0) = rk0;  *(uint4*)(Kh + lo0 + 256) = rk1;
        *(uint4*)(Kl + lo0) = rl0;  *(uint4*)(Kl + lo0 + 256) = rl1;
        *(uint4*)(Vh + lo0) = rv0;  *(uint4*)(Vh + lo0 + 256) = rv1;
        *(uint4*)(Vl + lo0) = rw0;  *(uint4*)(Vl + lo0 + 256) = rw1;
        __syncthreads();            // staged and visible
        if (st < 15) LOADKV(st + 1);   // prefetch overlaps compute
        // S = Q K^T (wave strip 16 x 64), 3-MFMA split
        f32x4 sacc[4];
        #pragma unroll
        for (int nt = 0; nt < 4; ++nt) sacc[nt] = (f32x4){0.f, 0.f, 0.f, 0.f};
        #pragma unroll
        for (int nt = 0; nt < 4; ++nt)
            #pragma unroll
            for (int kk = 0; kk < 2; ++kk) {
                bf16x8 kbh = *(const bf16x8*)(Kh + (kk * 4 + nt) * 512 + lane * 8);
                bf16x8 kbl = *(const bf16x8*)(Kl + (kk * 4 + nt) * 512 + lane * 8);
                sacc[nt] = __builtin_amdgcn_mfma_f32_16x16x32_bf16(aqh[kk], kbh, sacc[nt], 0, 0, 0);
                sacc[nt] = __builtin_amdgcn_mfma_f32_16x16x32_bf16(aqh[kk], kbl, sacc[nt], 0, 0, 0);
                sacc[nt] = __builtin_amdgcn_mfma_f32_16x16x32_bf16(aql[kk], kbh, sacc[nt], 0, 0, 0);
            }
        // online softmax per owned row (row = w*16 + quad*4 + rg)
        #pragma unroll
        for (int rg = 0; rg < 4; ++rg) {
            float mx = fmaxf(fmaxf(sacc[0][rg], sacc[1][rg]),
                             fmaxf(sacc[2][rg], sacc[3][rg]));
            #pragma unroll
            for (int msk = 1; msk < 16; msk <<= 1) mx = fmaxf(mx, __shfl_xor(mx, msk));
            float mn = fmaxf(m_i[rg], mx);
            float al = __expf(m_i[rg] - mn);
            float p0 = __expf(sacc[0][rg] - mn);
            float p1 = __expf(sacc[1][rg] - mn);
            float p2 = __expf(sacc[2][rg] - mn);
            float p3 = __expf(sacc[3][rg] - mn);
            float rs = p0 + p1 + p2 + p3;
            #pragma unroll
            for (int msk = 1; msk < 16; msk <<= 1) rs += __shfl_xor(rs, msk);
            l_i[rg] = l_i[rg] * al + rs;
            m_i[rg] = mn;
            #pragma unroll
            for (int dn = 0; dn < 4; ++dn) Oacc[dn][rg] *= al;
            int row = w * 16 + quad * 4 + rg;
            Ps[row * 72 +  0 + fr] = bf16_hi(p0);
            Ps[row * 72 + 16 + fr] = bf16_hi(p1);
            Ps[row * 72 + 32 + fr] = bf16_hi(p2);
            Ps[row * 72 + 48 + fr] = bf16_hi(p3);
        }
        // O += P V (P wave-private; V staged this stage)
        #pragma unroll
        for (int kk = 0; kk < 2; ++kk) {
            bf16x8 pa = *(const bf16x8*)&Ps[(w * 16 + fr) * 72 + fq + kk * 32];
            #pragma unroll
            for (int dn = 0; dn < 4; ++dn) {
                bf16x8 vbh = *(const bf16x8*)(Vh + (kk * 4 + dn) * 512 + lane * 8);
                bf16x8 vbl = *(const bf16x8*)(Vl + (kk * 4 + dn) * 512 + lane * 8);
                Oacc[dn] = __builtin_amdgcn_mfma_f32_16x16x32_bf16(pa, vbh, Oacc[dn], 0, 0, 0);
                Oacc[dn] = __builtin_amdgcn_mfma_f32_16x16x32_bf16(pa, vbl, Oacc[dn], 0, 0, 0);
            }
        }
    }
    #undef LOADKV
    // epilogue: normalize, sigmoid gate, split-store y
    float inv[4];
    #pragma unroll
    for (int rg = 0; rg < 4; ++rg) inv[rg] = 1.0f / l_i[rg];
    #pragma unroll
    for (int dn = 0; dn < 4; ++dn) {
        int ch = h * 64 + dn * 16 + fr;
        #pragma unroll
        for (int rg = 0; rg < 4; ++rg) {
            int tok = b * 1024 + qt * 64 + w * 16 + quad * 4 + rg;
            float gv = bf16_f(gbf[(size_t)tok * 768 + ch]);
            float sg = 1.0f / (1.0f + __expf(-gv));
            float val = Oacc[dn][rg] * inv[rg] * sg;
            u16 hh, ll;
            split_bf16(val, hh, ll);
            yh[(size_t)tok * 768 + ch] = hh;
            yl[(size_t)tok * 768 + ch] = ll;
        }
    }
}

// ---------------------------------------------------------------------------
// Kernel 4: out = y @ Wo^T + bo -> (B, C, T), split-bf16 16x16x32 MFMA,
// register-double-buffer + fragment-ordered LDS.
// ---------------------------------------------------------------------------
__global__ __launch_bounds__(256, 2) void out_mfma(
    const u16* __restrict__ yh, const u16* __restrict__ yl,
    const u16* __restrict__ woh, const u16* __restrict__ wol,
    const float* __restrict__ bo, float* __restrict__ out) {
    int bx = blockIdx.x;   // c tile 0..5
    int by = blockIdx.y;   // t tile 0..63
    int m0 = bx * 128;     // c
    int n0 = by * 128;     // t

    __shared__ u16 Ah[4096], Al[4096], Bh[4096], Bl[4096];

    int tid  = threadIdx.x;
    int lane = tid & 63, wid = tid >> 6;
    int wm = (wid & 1) * 64, wn = (wid >> 1) * 64;
    int fr = lane & 15, rq = (lane >> 4) * 4;

    f32x4 acc[4][4];
    #pragma unroll
    for (int i = 0; i < 4; ++i)
        #pragma unroll
        for (int j = 0; j < 4; ++j)
            acc[i][j] = (f32x4){0.f, 0.f, 0.f, 0.f};

    int j = tid >> 5, u = tid & 31;
    size_t offA = (size_t)(m0 + j * 16 + (u & 15)) * 768 + (u >> 4) * 8;
    size_t offB = (size_t)(n0 + j * 16 + (u & 15)) * 768 + (u >> 4) * 8;
    int lo0 = j * 512 + u * 8;
    int ba = (wm >> 4), bb2 = (wn >> 4);

    uint4 pa0, pa1, pb0, pb1, pc0, pc1, pd0, pd1;
    #define LOADTILE(K) do { \
        pa0 = *(const uint4*)(woh + offA + (K)); \
        pa1 = *(const uint4*)(woh + offA + (K) + 16); \
        pb0 = *(const uint4*)(wol + offA + (K)); \
        pb1 = *(const uint4*)(wol + offA + (K) + 16); \
        pc0 = *(const uint4*)(yh + offB + (K)); \
        pc1 = *(const uint4*)(yh + offB + (K) + 16); \
        pd0 = *(const uint4*)(yl + offB + (K)); \
        pd1 = *(const uint4*)(yl + offB + (K) + 16); \
    } while (0)

    LOADTILE(0);
    for (int k0 = 0; k0 < 768; k0 += 32) {
        __syncthreads();
        *(uint4*)(Ah + lo0) = pa0;  *(uint4*)(Ah + lo0 + 256) = pa1;
        *(uint4*)(Al + lo0) = pb0;  *(uint4*)(Al + lo0 + 256) = pb1;
        *(uint4*)(Bh + lo0) = pc0;  *(uint4*)(Bh + lo0 + 256) = pc1;
        *(uint4*)(Bl + lo0) = pd0;  *(uint4*)(Bl + lo0 + 256) = pd1;
        __syncthreads();
        if (k0 + 32 < 768) LOADTILE(k0 + 32);
        bf16x8 fah[4], fal[4], fbh[4], fbl[4];
        #pragma unroll
        for (int i = 0; i < 4; ++i) {
            fah[i] = *(const bf16x8*)(Ah + (ba + i) * 512 + lane * 8);
            fal[i] = *(const bf16x8*)(Al + (ba + i) * 512 + lane * 8);
            fbh[i] = *(const bf16x8*)(Bh + (bb2 + i) * 512 + lane * 8);
            fbl[i] = *(const bf16x8*)(Bl + (bb2 + i) * 512 + lane * 8);
        }
        #pragma unroll
        for (int mi = 0; mi < 4; ++mi)
            #pragma unroll
            for (int ni = 0; ni < 4; ++ni) {
                acc[mi][ni] = __builtin_amdgcn_mfma_f32_16x16x32_bf16(fah[mi], fbh[ni], acc[mi][ni], 0, 0, 0);
                acc[mi][ni] = __builtin_amdgcn_mfma_f32_16x16x32_bf16(fah[mi], fbl[ni], acc[mi][ni], 0, 0, 0);
                acc[mi][ni] = __builtin_amdgcn_mfma_f32_16x16x32_bf16(fal[mi], fbh[ni], acc[mi][ni], 0, 0, 0);
            }
    }
    #undef LOADTILE
    int bb = n0 >> 10;
    #pragma unroll
    for (int ni = 0; ni < 4; ++ni) {
        int colg = n0 + wn + ni * 16 + fr;
        int tl = colg & 1023;
        #pragma unroll
        for (int mi = 0; mi < 4; ++mi) {
            int row = m0 + wm + mi * 16 + rq;
            #pragma unroll
            for (int rg = 0; rg < 4; ++rg) {
                float val = acc[mi][ni][rg] + bo[row + rg];
                out[((size_t)bb * 768 + row + rg) * 1024 + tl] = val;
            }
        }
    }
}

extern "C" void kernel_launch(void* const* d_in, const int* in_sizes, int n_in,
                              void* d_out, int out_size, void* d_ws, size_t ws_size,
                              hipStream_t stream) {
    const float* x     = (const float*)d_in[0];
    const float* Wq    = (const float*)d_in[1];
    const float* bq    = (const float*)d_in[2];
    const float* Wk    = (const float*)d_in[3];
    const float* bk    = (const float*)d_in[4];
    const float* Wv    = (const float*)d_in[5];
    const float* bv    = (const float*)d_in[6];
    const float* Wo    = (const float*)d_in[7];
    const float* bo    = (const float*)d_in[8];
    const float* Wg    = (const float*)d_in[9];
    const float* bg    = (const float*)d_in[10];
    const float* gamma = (const float*)d_in[11];
    const float* beta  = (const float*)d_in[12];
    float* out = (float*)d_out;

    // workspace (ushort): xn_h|xn_l|qh|ql|kh|kl|vth|vtl|g | wbuf
    const size_t S = (size_t)BT_ * C_;
    u16* xn_hi = (u16*)d_ws;
    u16* xn_lo = xn_hi + S;
    u16* qh    = xn_lo + S;
    u16* ql    = qh + S;
    u16* kh    = ql + S;
    u16* kl    = kh + S;
    u16* vth   = kl + S;
    u16* vtl   = vth + S;
    u16* g_bf  = vtl + S;
    u16* wbuf  = g_bf + S;   // [Wq,Wk,Wv,Wg,Wo] x {hi,lo}
    u16* y_hi  = xn_hi;      // alias: xn dead after qkvg
    u16* y_lo  = xn_lo;

    wconv_all<<<dim3(WSZ / 1024, 5), 256, 0, stream>>>(Wq, Wk, Wv, Wg, Wo, wbuf);
    ln_kernel<<<BT_, 256, 0, stream>>>(x, gamma, beta, xn_hi, xn_lo);
    qkvg_mfma<<<dim3(64, 24), 256, 0, stream>>>(xn_hi, xn_lo, wbuf,
                                                bq, bk, bv, bg,
                                                qh, ql, kh, kl, vth, vtl, g_bf);
    attn_mfma<<<dim3(16, 12, 8), 256, 0, stream>>>(qh, ql, kh, kl, vth, vtl,
                                                   g_bf, y_hi, y_lo);
    out_mfma<<<dim3(6, 64), 256, 0, stream>>>(y_hi, y_lo,
                                              wbuf + (size_t)8 * WSZ,
                                              wbuf + (size_t)9 * WSZ, bo, out);
}

// Round 8
// 424.743 us; speedup vs baseline: 2.6251x; 1.0889x over previous
//
#include <hip/hip_runtime.h>
#include <math.h>

#define B_   8
#define C_   768
#define T_   1024
#define NH_  12
#define DH_  64
#define BT_  (B_*T_)       // 8192
#define WSZ  (C_*C_)       // 589824 per weight matrix

using bf16x8 = __attribute__((ext_vector_type(8))) short;
using f32x4  = __attribute__((ext_vector_type(4))) float;
typedef unsigned short u16;

// ---- bf16 split helpers (round-to-nearest-even) ----
__device__ inline u16 bf16_hi(float x) {
    unsigned u = __builtin_bit_cast(unsigned, x);
    u = (u + 0x7fffu + ((u >> 16) & 1u)) >> 16;
    return (u16)u;
}
__device__ inline float bf16_f(u16 h) {
    unsigned u = ((unsigned)h) << 16;
    return __builtin_bit_cast(float, u);
}
__device__ inline void split_bf16(float x, u16& h, u16& l) {
    h = bf16_hi(x);
    l = bf16_hi(x - bf16_f(h));
}

// ---------------------------------------------------------------------------
// Kernel 0: all 5 weight mats fp32 -> bf16 hi/lo split in one launch.
// ---------------------------------------------------------------------------
__global__ __launch_bounds__(256) void wconv_all(
    const float* __restrict__ W0, const float* __restrict__ W1,
    const float* __restrict__ W2, const float* __restrict__ W3,
    const float* __restrict__ W4, u16* __restrict__ wbuf) {
    int mat = blockIdx.y;
    const float* W = (mat == 0) ? W0 : (mat == 1) ? W1 : (mat == 2) ? W2
                   : (mat == 3) ? W3 : W4;
    u16* hi = wbuf + (size_t)mat * 2 * WSZ;
    u16* lo = hi + WSZ;
    int i = (blockIdx.x * 256 + threadIdx.x) * 4;
    float4 w = *(const float4*)(W + i);
    ushort4 h, l;
    split_bf16(w.x, h.x, l.x);
    split_bf16(w.y, h.y, l.y);
    split_bf16(w.z, h.z, l.z);
    split_bf16(w.w, h.w, l.w);
    *(ushort4*)(hi + i) = h;
    *(ushort4*)(lo + i) = l;
}

// ---------------------------------------------------------------------------
// Kernel 1: LayerNorm with (B,C,T)->(B*T,C) transpose; writes bf16 hi/lo.
// ---------------------------------------------------------------------------
__global__ __launch_bounds__(256) void ln_kernel(const float* __restrict__ x,
                                                 const float* __restrict__ gamma,
                                                 const float* __restrict__ beta,
                                                 u16* __restrict__ xh,
                                                 u16* __restrict__ xl) {
    int row = blockIdx.x;
    int b = row >> 10;
    int t = row & 1023;
    int tid = threadIdx.x;
    const float* xb = x + (size_t)b * C_ * T_ + t;
    float v0 = xb[(size_t)(tid      ) * T_];
    float v1 = xb[(size_t)(tid + 256) * T_];
    float v2 = xb[(size_t)(tid + 512) * T_];
    float s  = v0 + v1 + v2;
    float sq = v0 * v0 + v1 * v1 + v2 * v2;
    #pragma unroll
    for (int m = 1; m < 64; m <<= 1) {
        s  += __shfl_xor(s,  m);
        sq += __shfl_xor(sq, m);
    }
    __shared__ float ss[4], ssq[4];
    int wid = tid >> 6;
    if ((tid & 63) == 0) { ss[wid] = s; ssq[wid] = sq; }
    __syncthreads();
    s  = ss[0] + ss[1] + ss[2] + ss[3];
    sq = ssq[0] + ssq[1] + ssq[2] + ssq[3];
    float mu   = s * (1.0f / 768.0f);
    float var  = sq * (1.0f / 768.0f) - mu * mu;
    float rstd = 1.0f / sqrtf(var + 1e-5f);
    size_t o = (size_t)row * C_;
    float r0 = (v0 - mu) * rstd * gamma[tid      ] + beta[tid      ];
    float r1 = (v1 - mu) * rstd * gamma[tid + 256] + beta[tid + 256];
    float r2 = (v2 - mu) * rstd * gamma[tid + 512] + beta[tid + 512];
    u16 h, l;
    split_bf16(r0, h, l); xh[o + tid      ] = h; xl[o + tid      ] = l;
    split_bf16(r1, h, l); xh[o + tid + 256] = h; xl[o + tid + 256] = l;
    split_bf16(r2, h, l); xh[o + tid + 512] = h; xl[o + tid + 512] = l;
}

// ---------------------------------------------------------------------------
// Kernel 2: fused QKVG GEMM, split-bf16 compute (3 MFMA; gate 1 MFMA),
// PLAIN bf16 outputs (q pre-scaled 1/8; V as V^T [b,h,d,t]).
// Single-barrier LDS double-buffer + 2-tile-deep register prefetch.
// Fragment-ordered LDS; unconditional loads (clamped addr) to avoid the R6
// conditional-assignment spill.
// ---------------------------------------------------------------------------
__global__ __launch_bounds__(256, 2) void qkvg_mfma(
    const u16* __restrict__ xh, const u16* __restrict__ xl,
    const u16* __restrict__ wmats,
    const float* __restrict__ bq, const float* __restrict__ bk,
    const float* __restrict__ bv, const float* __restrict__ bg,
    u16* __restrict__ qh, u16* __restrict__ kh,
    u16* __restrict__ vth, u16* __restrict__ g) {
    int bx = blockIdx.x;            // m tile 0..63
    int by = blockIdx.y;            // 0..23
    int mat = by / 6;
    int n0  = (by % 6) * 128;
    int m0  = bx * 128;
    const u16* Wh = wmats + (size_t)mat * 2 * WSZ;
    const u16* Wl = Wh + WSZ;
    const float* bias = (mat == 0) ? bq : (mat == 1) ? bk : (mat == 2) ? bv : bg;

    __shared__ u16 Ah[2 * 4096], Al[2 * 4096], Bh[2 * 4096], Bl[2 * 4096];

    int tid  = threadIdx.x;
    int lane = tid & 63, wid = tid >> 6;
    int wm = (wid & 1) * 64, wn = (wid >> 1) * 64;
    int fr = lane & 15, rq = (lane >> 4) * 4;

    f32x4 acc[4][4];
    #pragma unroll
    for (int i = 0; i < 4; ++i)
        #pragma unroll
        for (int j = 0; j < 4; ++j)
            acc[i][j] = (f32x4){0.f, 0.f, 0.f, 0.f};

    int j = tid >> 5, u = tid & 31;
    size_t offA = (size_t)(m0 + j * 16 + (u & 15)) * 768 + (u >> 4) * 8;
    size_t offB = (size_t)(n0 + j * 16 + (u & 15)) * 768 + (u >> 4) * 8;
    int lo0 = j * 512 + u * 8;      // u16 units
    int ba = (wm >> 4), bb2 = (wn >> 4);

    uint4 pa0, pa1, pb0, pb1, pc0, pc1, pd0, pd1;
    #define LOADTILE(K) do { \
        pa0 = *(const uint4*)(xh + offA + (K)); \
        pa1 = *(const uint4*)(xh + offA + (K) + 16); \
        pb0 = *(const uint4*)(xl + offA + (K)); \
        pb1 = *(const uint4*)(xl + offA + (K) + 16); \
        pc0 = *(const uint4*)(Wh + offB + (K)); \
        pc1 = *(const uint4*)(Wh + offB + (K) + 16); \
        pd0 = *(const uint4*)(Wl + offB + (K)); \
        pd1 = *(const uint4*)(Wl + offB + (K) + 16); \
    } while (0)
    #define STORES(BUF) do { \
        int lb = (BUF) * 4096 + lo0; \
        *(uint4*)(Ah + lb) = pa0;  *(uint4*)(Ah + lb + 256) = pa1; \
        *(uint4*)(Al + lb) = pb0;  *(uint4*)(Al + lb + 256) = pb1; \
        *(uint4*)(Bh + lb) = pc0;  *(uint4*)(Bh + lb + 256) = pc1; \
        *(uint4*)(Bl + lb) = pd0;  *(uint4*)(Bl + lb + 256) = pd1; \
    } while (0)

    LOADTILE(0);
    STORES(0);
    LOADTILE(32);
    __syncthreads();
    int cur = 0;
    for (int k0 = 0; k0 < 768; k0 += 32) {
        int nxt = cur ^ 1;
        STORES(nxt);                       // tile k0+32 (garbage on last iter, never read)
        int k2 = (k0 + 64 < 768) ? (k0 + 64) : 0;   // clamped addr, unconditional load
        LOADTILE(k2);
        bf16x8 fah[4], fal[4], fbh[4], fbl[4];
        #pragma unroll
        for (int i = 0; i < 4; ++i) {
            fah[i] = *(const bf16x8*)(Ah + cur * 4096 + (ba + i) * 512 + lane * 8);
            fal[i] = *(const bf16x8*)(Al + cur * 4096 + (ba + i) * 512 + lane * 8);
            fbh[i] = *(const bf16x8*)(Bh + cur * 4096 + (bb2 + i) * 512 + lane * 8);
            fbl[i] = *(const bf16x8*)(Bl + cur * 4096 + (bb2 + i) * 512 + lane * 8);
        }
        if (mat == 2) {
            #pragma unroll
            for (int mi = 0; mi < 4; ++mi)
                #pragma unroll
                for (int ni = 0; ni < 4; ++ni) {
                    acc[mi][ni] = __builtin_amdgcn_mfma_f32_16x16x32_bf16(fbh[ni], fah[mi], acc[mi][ni], 0, 0, 0);
                    acc[mi][ni] = __builtin_amdgcn_mfma_f32_16x16x32_bf16(fbh[ni], fal[mi], acc[mi][ni], 0, 0, 0);
                    acc[mi][ni] = __builtin_amdgcn_mfma_f32_16x16x32_bf16(fbl[ni], fah[mi], acc[mi][ni], 0, 0, 0);
                }
        } else if (mat != 3) {
            #pragma unroll
            for (int mi = 0; mi < 4; ++mi)
                #pragma unroll
                for (int ni = 0; ni < 4; ++ni) {
                    acc[mi][ni] = __builtin_amdgcn_mfma_f32_16x16x32_bf16(fah[mi], fbh[ni], acc[mi][ni], 0, 0, 0);
                    acc[mi][ni] = __builtin_amdgcn_mfma_f32_16x16x32_bf16(fah[mi], fbl[ni], acc[mi][ni], 0, 0, 0);
                    acc[mi][ni] = __builtin_amdgcn_mfma_f32_16x16x32_bf16(fal[mi], fbh[ni], acc[mi][ni], 0, 0, 0);
                }
        } else {   // gate: plain bf16
            #pragma unroll
            for (int mi = 0; mi < 4; ++mi)
                #pragma unroll
                for (int ni = 0; ni < 4; ++ni)
                    acc[mi][ni] = __builtin_amdgcn_mfma_f32_16x16x32_bf16(fah[mi], fbh[ni], acc[mi][ni], 0, 0, 0);
        }
        __syncthreads();
        cur = nxt;
    }
    #undef LOADTILE
    #undef STORES
    // epilogue: C/D layout col=lane&15, row=(lane>>4)*4+reg; plain bf16 out
    if (mat == 2) {
        int bb = m0 >> 10;
        #pragma unroll
        for (int mi = 0; mi < 4; ++mi) {
            int tok = m0 + wm + mi * 16 + fr;
            int tl  = tok & 1023;
            #pragma unroll
            for (int ni = 0; ni < 4; ++ni) {
                #pragma unroll
                for (int rg = 0; rg < 4; ++rg) {
                    int ch = n0 + wn + ni * 16 + rq + rg;
                    float val = acc[mi][ni][rg] + bias[ch];
                    size_t addr = ((size_t)((bb * 12 + (ch >> 6)) * 64 + (ch & 63))) * 1024 + tl;
                    vth[addr] = bf16_hi(val);
                }
            }
        }
    } else {
        u16* oh = (mat == 0) ? qh : (mat == 1) ? kh : g;
        float scale = (mat == 0) ? 0.125f : 1.0f;
        #pragma unroll
        for (int ni = 0; ni < 4; ++ni) {
            int col = n0 + wn + ni * 16 + fr;
            float bb = bias[col];
            #pragma unroll
            for (int mi = 0; mi < 4; ++mi) {
                int row = m0 + wm + mi * 16 + rq;
                #pragma unroll
                for (int rg = 0; rg < 4; ++rg) {
                    float val = (acc[mi][ni][rg] + bb) * scale;
                    oh[(size_t)(row + rg) * 768 + col] = bf16_hi(val);
                }
            }
        }
    }
}

// ---------------------------------------------------------------------------
// Kernel 3: MFMA flash attention, plain-bf16 q/k/v (values were computed
// split-accurately then RNE-rounded). 8 QK + 8 PV MFMA per wave-stage.
// Single-barrier LDS double-buffer, 2-stage-deep register prefetch.
// P via wave-private LDS strip (no barrier needed).
// ---------------------------------------------------------------------------
__global__ __launch_bounds__(256, 3) void attn_mfma(
    const u16* __restrict__ qhg, const u16* __restrict__ khg,
    const u16* __restrict__ vthg, const u16* __restrict__ gbf,
    u16* __restrict__ yh, u16* __restrict__ yl) {
    int qt = blockIdx.x;   // 0..15
    int h  = blockIdx.y;   // 0..11
    int b  = blockIdx.z;   // 0..7
    __shared__ u16 Kh[2 * 4096], Vh[2 * 4096];
    __shared__ u16 Ps[64 * 72];
    int tid = threadIdx.x;
    int lane = tid & 63, w = tid >> 6;
    int fr = lane & 15, quad = lane >> 4, fq = quad * 8;

    size_t qbase = ((size_t)(b * 1024 + qt * 64)) * 768 + h * 64;
    size_t kbase = ((size_t)(b * 1024)) * 768 + h * 64;
    size_t vbase = ((size_t)((b * 12 + h) * 64)) * 1024;

    // Q A-fragments direct from global (loop-invariant, pre-scaled 1/8)
    bf16x8 aq[2];
    #pragma unroll
    for (int kk = 0; kk < 2; ++kk)
        aq[kk] = *(const bf16x8*)(qhg + qbase + (size_t)(w * 16 + fr) * 768 + kk * 32 + fq);

    float m_i[4], l_i[4];
    f32x4 Oacc[4];
    #pragma unroll
    for (int i = 0; i < 4; ++i) {
        m_i[i] = -1e30f; l_i[i] = 0.0f;
        Oacc[i] = (f32x4){0.f, 0.f, 0.f, 0.f};
    }

    // staging geometry: block j=t>>5 (kk=j>>2, nt/dn=j&3)
    int j = tid >> 5, u = tid & 31;
    int kk_ = j >> 2, nd_ = j & 3;
    size_t offK = kbase + (size_t)(nd_ * 16 + (u & 15)) * 768 + kk_ * 32 + (u >> 4) * 8;
    size_t offV = vbase + (size_t)(nd_ * 16 + (u & 15)) * 1024 + kk_ * 32 + (u >> 4) * 8;
    int lo0 = j * 512 + u * 8;

    uint4 rk0, rk1, rv0, rv1;
    #define LOADKV(ST) do { \
        size_t ok = offK + (size_t)(ST) * 49152; \
        size_t ov = offV + (size_t)(ST) * 64; \
        rk0 = *(const uint4*)(khg + ok);  rk1 = *(const uint4*)(khg + ok + 16); \
        rv0 = *(const uint4*)(vthg + ov); rv1 = *(const uint4*)(vthg + ov + 16); \
    } while (0)
    #define STOREKV(BUF) do { \
        int lb = (BUF) * 4096 + lo0; \
        *(uint4*)(Kh + lb) = rk0;  *(uint4*)(Kh + lb + 256) = rk1; \
        *(uint4*)(Vh + lb) = rv0;  *(uint4*)(Vh + lb + 256) = rv1; \
    } while (0)

    LOADKV(0);
    STOREKV(0);
    LOADKV(1);
    __syncthreads();
    int cur = 0;
    for (int st = 0; st < 16; ++st) {
        int nxt = cur ^ 1;
        STOREKV(nxt);                  // stage st+1 (garbage on last, never read)
        int s2 = (st + 2 < 16) ? (st + 2) : 0;
        LOADKV(s2);
        // S = Q K^T (wave strip 16 x 64)
        f32x4 sacc[4];
        #pragma unroll
        for (int nt = 0; nt < 4; ++nt) sacc[nt] = (f32x4){0.f, 0.f, 0.f, 0.f};
        #pragma unroll
        for (int nt = 0; nt < 4; ++nt)
            #pragma unroll
            for (int kk = 0; kk < 2; ++kk) {
                bf16x8 kb = *(const bf16x8*)(Kh + cur * 4096 + (kk * 4 + nt) * 512 + lane * 8);
                sacc[nt] = __builtin_amdgcn_mfma_f32_16x16x32_bf16(aq[kk], kb, sacc[nt], 0, 0, 0);
            }
        // online softmax per owned row (row = w*16 + quad*4 + rg)
        #pragma unroll
        for (int rg = 0; rg < 4; ++rg) {
            float mx = fmaxf(fmaxf(sacc[0][rg], sacc[1][rg]),
                             fmaxf(sacc[2][rg], sacc[3][rg]));
            #pragma unroll
            for (int msk = 1; msk < 16; msk <<= 1) mx = fmaxf(mx, __shfl_xor(mx, msk));
            float mn = fmaxf(m_i[rg], mx);
            float al = __expf(m_i[rg] - mn);
            float p0 = __expf(sacc[0][rg] - mn);
            float p1 = __expf(sacc[1][rg] - mn);
            float p2 = __expf(sacc[2][rg] - mn);
            float p3 = __expf(sacc[3][rg] - mn);
            float rs = p0 + p1 + p2 + p3;
            #pragma unroll
            for (int msk = 1; msk < 16; msk <<= 1) rs += __shfl_xor(rs, msk);
            l_i[rg] = l_i[rg] * al + rs;
            m_i[rg] = mn;
            #pragma unroll
            for (int dn = 0; dn < 4; ++dn) Oacc[dn][rg] *= al;
            int row = w * 16 + quad * 4 + rg;
            Ps[row * 72 +  0 + fr] = bf16_hi(p0);
            Ps[row * 72 + 16 + fr] = bf16_hi(p1);
            Ps[row * 72 + 32 + fr] = bf16_hi(p2);
            Ps[row * 72 + 48 + fr] = bf16_hi(p3);
        }
        // O += P V (P wave-private rows; V in buf[cur])
        #pragma unroll
        for (int kk = 0; kk < 2; ++kk) {
            bf16x8 pa = *(const bf16x8*)&Ps[(w * 16 + fr) * 72 + fq + kk * 32];
            #pragma unroll
            for (int dn = 0; dn < 4; ++dn) {
                bf16x8 vb = *(const bf16x8*)(Vh + cur * 4096 + (kk * 4 + dn) * 512 + lane * 8);
                Oacc[dn] = __builtin_amdgcn_mfma_f32_16x16x32_bf16(pa, vb, Oacc[dn], 0, 0, 0);
            }
        }
        __syncthreads();
        cur = nxt;
    }
    #undef LOADKV
    #undef STOREKV
    // epilogue: normalize, sigmoid gate, split-store y
    float inv[4];
    #pragma unroll
    for (int rg = 0; rg < 4; ++rg) inv[rg] = 1.0f / l_i[rg];
    #pragma unroll
    for (int dn = 0; dn < 4; ++dn) {
        int ch = h * 64 + dn * 16 + fr;
        #pragma unroll
        for (int rg = 0; rg < 4; ++rg) {
            int tok = b * 1024 + qt * 64 + w * 16 + quad * 4 + rg;
            float gv = bf16_f(gbf[(size_t)tok * 768 + ch]);
            float sg = 1.0f / (1.0f + __expf(-gv));
            float val = Oacc[dn][rg] * inv[rg] * sg;
            u16 hh, ll;
            split_bf16(val, hh, ll);
            yh[(size_t)tok * 768 + ch] = hh;
            yl[(size_t)tok * 768 + ch] = ll;
        }
    }
}

// ---------------------------------------------------------------------------
// Kernel 4: out = y @ Wo^T + bo -> (B, C, T), split-bf16 16x16x32 MFMA,
// single-barrier LDS double-buffer + register prefetch.
// ---------------------------------------------------------------------------
__global__ __launch_bounds__(256, 2) void out_mfma(
    const u16* __restrict__ yh, const u16* __restrict__ yl,
    const u16* __restrict__ woh, const u16* __restrict__ wol,
    const float* __restrict__ bo, float* __restrict__ out) {
    int bx = blockIdx.x;   // c tile 0..5
    int by = blockIdx.y;   // t tile 0..63
    int m0 = bx * 128;     // c
    int n0 = by * 128;     // t

    __shared__ u16 Ah[2 * 4096], Al[2 * 4096], Bh[2 * 4096], Bl[2 * 4096];

    int tid  = threadIdx.x;
    int lane = tid & 63, wid = tid >> 6;
    int wm = (wid & 1) * 64, wn = (wid >> 1) * 64;
    int fr = lane & 15, rq = (lane >> 4) * 4;

    f32x4 acc[4][4];
    #pragma unroll
    for (int i = 0; i < 4; ++i)
        #pragma unroll
        for (int j = 0; j < 4; ++j)
            acc[i][j] = (f32x4){0.f, 0.f, 0.f, 0.f};

    int j = tid >> 5, u = tid & 31;
    size_t offA = (size_t)(m0 + j * 16 + (u & 15)) * 768 + (u >> 4) * 8;
    size_t offB = (size_t)(n0 + j * 16 + (u & 15)) * 768 + (u >> 4) * 8;
    int lo0 = j * 512 + u * 8;
    int ba = (wm >> 4), bb2 = (wn >> 4);

    uint4 pa0, pa1, pb0, pb1, pc0, pc1, pd0, pd1;
    #define LOADTILE(K) do { \
        pa0 = *(const uint4*)(woh + offA + (K)); \
        pa1 = *(const uint4*)(woh + offA + (K) + 16); \
        pb0 = *(const uint4*)(wol + offA + (K)); \
        pb1 = *(const uint4*)(wol + offA + (K) + 16); \
        pc0 = *(const uint4*)(yh + offB + (K)); \
        pc1 = *(const uint4*)(yh + offB + (K) + 16); \
        pd0 = *(const uint4*)(yl + offB + (K)); \
        pd1 = *(const uint4*)(yl + offB + (K) + 16); \
    } while (0)
    #define STORES(BUF) do { \
        int lb = (BUF) * 4096 + lo0; \
        *(uint4*)(Ah + lb) = pa0;  *(uint4*)(Ah + lb + 256) = pa1; \
        *(uint4*)(Al + lb) = pb0;  *(uint4*)(Al + lb + 256) = pb1; \
        *(uint4*)(Bh + lb) = pc0;  *(uint4*)(Bh + lb + 256) = pc1; \
        *(uint4*)(Bl + lb) = pd0;  *(uint4*)(Bl + lb + 256) = pd1; \
    } while (0)

    LOADTILE(0);
    STORES(0);
    LOADTILE(32);
    __syncthreads();
    int cur = 0;
    for (int k0 = 0; k0 < 768; k0 += 32) {
        int nxt = cur ^ 1;
        STORES(nxt);
        int k2 = (k0 + 64 < 768) ? (k0 + 64) : 0;
        LOADTILE(k2);
        bf16x8 fah[4], fal[4], fbh[4], fbl[4];
        #pragma unroll
        for (int i = 0; i < 4; ++i) {
            fah[i] = *(const bf16x8*)(Ah + cur * 4096 + (ba + i) * 512 + lane * 8);
            fal[i] = *(const bf16x8*)(Al + cur * 4096 + (ba + i) * 512 + lane * 8);
            fbh[i] = *(const bf16x8*)(Bh + cur * 4096 + (bb2 + i) * 512 + lane * 8);
            fbl[i] = *(const bf16x8*)(Bl + cur * 4096 + (bb2 + i) * 512 + lane * 8);
        }
        #pragma unroll
        for (int mi = 0; mi < 4; ++mi)
            #pragma unroll
            for (int ni = 0; ni < 4; ++ni) {
                acc[mi][ni] = __builtin_amdgcn_mfma_f32_16x16x32_bf16(fah[mi], fbh[ni], acc[mi][ni], 0, 0, 0);
                acc[mi][ni] = __builtin_amdgcn_mfma_f32_16x16x32_bf16(fah[mi], fbl[ni], acc[mi][ni], 0, 0, 0);
                acc[mi][ni] = __builtin_amdgcn_mfma_f32_16x16x32_bf16(fal[mi], fbh[ni], acc[mi][ni], 0, 0, 0);
            }
        __syncthreads();
        cur = nxt;
    }
    #undef LOADTILE
    #undef STORES
    int bb = n0 >> 10;
    #pragma unroll
    for (int ni = 0; ni < 4; ++ni) {
        int colg = n0 + wn + ni * 16 + fr;
        int tl = colg & 1023;
        #pragma unroll
        for (int mi = 0; mi < 4; ++mi) {
            int row = m0 + wm + mi * 16 + rq;
            #pragma unroll
            for (int rg = 0; rg < 4; ++rg) {
                float val = acc[mi][ni][rg] + bo[row + rg];
                out[((size_t)bb * 768 + row + rg) * 1024 + tl] = val;
            }
        }
    }
}

extern "C" void kernel_launch(void* const* d_in, const int* in_sizes, int n_in,
                              void* d_out, int out_size, void* d_ws, size_t ws_size,
                              hipStream_t stream) {
    const float* x     = (const float*)d_in[0];
    const float* Wq    = (const float*)d_in[1];
    const float* bq    = (const float*)d_in[2];
    const float* Wk    = (const float*)d_in[3];
    const float* bk    = (const float*)d_in[4];
    const float* Wv    = (const float*)d_in[5];
    const float* bv    = (const float*)d_in[6];
    const float* Wo    = (const float*)d_in[7];
    const float* bo    = (const float*)d_in[8];
    const float* Wg    = (const float*)d_in[9];
    const float* bg    = (const float*)d_in[10];
    const float* gamma = (const float*)d_in[11];
    const float* beta  = (const float*)d_in[12];
    float* out = (float*)d_out;

    // workspace (ushort): xn_h|xn_l|qh|kh|vth|g | wbuf ; y aliases xn
    const size_t S = (size_t)BT_ * C_;
    u16* xn_hi = (u16*)d_ws;
    u16* xn_lo = xn_hi + S;
    u16* qh    = xn_lo + S;
    u16* kh    = qh + S;
    u16* vth   = kh + S;
    u16* g_bf  = vth + S;
    u16* wbuf  = g_bf + S;   // [Wq,Wk,Wv,Wg,Wo] x {hi,lo}
    u16* y_hi  = xn_hi;      // alias: xn dead after qkvg
    u16* y_lo  = xn_lo;

    wconv_all<<<dim3(WSZ / 1024, 5), 256, 0, stream>>>(Wq, Wk, Wv, Wg, Wo, wbuf);
    ln_kernel<<<BT_, 256, 0, stream>>>(x, gamma, beta, xn_hi, xn_lo);
    qkvg_mfma<<<dim3(64, 24), 256, 0, stream>>>(xn_hi, xn_lo, wbuf,
                                                bq, bk, bv, bg,
                                                qh, kh, vth, g_bf);
    attn_mfma<<<dim3(16, 12, 8), 256, 0, stream>>>(qh, kh, vth, g_bf,
                                                   y_hi, y_lo);
    out_mfma<<<dim3(6, 64), 256, 0, stream>>>(y_hi, y_lo,
                                              wbuf + (size_t)8 * WSZ,
                                              wbuf + (size_t)9 * WSZ, bo, out);
}

// Round 9
// 384.992 us; speedup vs baseline: 2.8961x; 1.1033x over previous
//
#include <hip/hip_runtime.h>
#include <math.h>

#define B_   8
#define C_   768
#define T_   1024
#define NH_  12
#define DH_  64
#define BT_  (B_*T_)       // 8192
#define WSZ  (C_*C_)       // 589824 per weight matrix

using bf16x8 = __attribute__((ext_vector_type(8))) short;
using f32x4  = __attribute__((ext_vector_type(4))) float;
typedef unsigned short u16;

// ---- bf16 split helpers (round-to-nearest-even) ----
__device__ inline u16 bf16_hi(float x) {
    unsigned u = __builtin_bit_cast(unsigned, x);
    u = (u + 0x7fffu + ((u >> 16) & 1u)) >> 16;
    return (u16)u;
}
__device__ inline float bf16_f(u16 h) {
    unsigned u = ((unsigned)h) << 16;
    return __builtin_bit_cast(float, u);
}
__device__ inline void split_bf16(float x, u16& h, u16& l) {
    h = bf16_hi(x);
    l = bf16_hi(x - bf16_f(h));
}

// ---------------------------------------------------------------------------
// Kernel 0: all 5 weight mats fp32 -> bf16 hi/lo split in one launch.
// (lo of Wq/Wk/Wg is written but unused -- kernel is tiny, keep it uniform.)
// ---------------------------------------------------------------------------
__global__ __launch_bounds__(256) void wconv_all(
    const float* __restrict__ W0, const float* __restrict__ W1,
    const float* __restrict__ W2, const float* __restrict__ W3,
    const float* __restrict__ W4, u16* __restrict__ wbuf) {
    int mat = blockIdx.y;
    const float* W = (mat == 0) ? W0 : (mat == 1) ? W1 : (mat == 2) ? W2
                   : (mat == 3) ? W3 : W4;
    u16* hi = wbuf + (size_t)mat * 2 * WSZ;
    u16* lo = hi + WSZ;
    int i = (blockIdx.x * 256 + threadIdx.x) * 4;
    float4 w = *(const float4*)(W + i);
    ushort4 h, l;
    split_bf16(w.x, h.x, l.x);
    split_bf16(w.y, h.y, l.y);
    split_bf16(w.z, h.z, l.z);
    split_bf16(w.w, h.w, l.w);
    *(ushort4*)(hi + i) = h;
    *(ushort4*)(lo + i) = l;
}

// ---------------------------------------------------------------------------
// Kernel 1: LayerNorm with (B,C,T)->(B*T,C) transpose; writes bf16 hi/lo.
// ---------------------------------------------------------------------------
__global__ __launch_bounds__(256) void ln_kernel(const float* __restrict__ x,
                                                 const float* __restrict__ gamma,
                                                 const float* __restrict__ beta,
                                                 u16* __restrict__ xh,
                                                 u16* __restrict__ xl) {
    int row = blockIdx.x;
    int b = row >> 10;
    int t = row & 1023;
    int tid = threadIdx.x;
    const float* xb = x + (size_t)b * C_ * T_ + t;
    float v0 = xb[(size_t)(tid      ) * T_];
    float v1 = xb[(size_t)(tid + 256) * T_];
    float v2 = xb[(size_t)(tid + 512) * T_];
    float s  = v0 + v1 + v2;
    float sq = v0 * v0 + v1 * v1 + v2 * v2;
    #pragma unroll
    for (int m = 1; m < 64; m <<= 1) {
        s  += __shfl_xor(s,  m);
        sq += __shfl_xor(sq, m);
    }
    __shared__ float ss[4], ssq[4];
    int wid = tid >> 6;
    if ((tid & 63) == 0) { ss[wid] = s; ssq[wid] = sq; }
    __syncthreads();
    s  = ss[0] + ss[1] + ss[2] + ss[3];
    sq = ssq[0] + ssq[1] + ssq[2] + ssq[3];
    float mu   = s * (1.0f / 768.0f);
    float var  = sq * (1.0f / 768.0f) - mu * mu;
    float rstd = 1.0f / sqrtf(var + 1e-5f);
    size_t o = (size_t)row * C_;
    float r0 = (v0 - mu) * rstd * gamma[tid      ] + beta[tid      ];
    float r1 = (v1 - mu) * rstd * gamma[tid + 256] + beta[tid + 256];
    float r2 = (v2 - mu) * rstd * gamma[tid + 512] + beta[tid + 512];
    u16 h, l;
    split_bf16(r0, h, l); xh[o + tid      ] = h; xl[o + tid      ] = l;
    split_bf16(r1, h, l); xh[o + tid + 256] = h; xl[o + tid + 256] = l;
    split_bf16(r2, h, l); xh[o + tid + 512] = h; xl[o + tid + 512] = l;
}

// ---------------------------------------------------------------------------
// Kernel 2: fused QKVG GEMM, 16x16x32 MFMA.
// Precision budget (R8 evidence: plain-bf16-stored q/k/v kept absmax 9.77e-4):
//   q, k, gate: PLAIN bf16 GEMM (1 MFMA) -- GEMM error ~ rounding error,
//               damped through softmax;
//   v:          split-bf16 (3 MFMA) -- error propagates linearly to out.
// Simple 2-barrier single-buffer structure (R3-era 157 us structure): 32 KB
// LDS -> 4 blocks/CU; TLP hides the staging latency (m114).
// Fragment-ordered LDS: block j (512 u16) = one 16x32 fragment; stores and
// reads both stride-16B -> conflict-free.
// ---------------------------------------------------------------------------
__global__ __launch_bounds__(256, 2) void qkvg_mfma(
    const u16* __restrict__ xh, const u16* __restrict__ xl,
    const u16* __restrict__ wmats,
    const float* __restrict__ bq, const float* __restrict__ bk,
    const float* __restrict__ bv, const float* __restrict__ bg,
    u16* __restrict__ qh, u16* __restrict__ kh,
    u16* __restrict__ vth, u16* __restrict__ g) {
    int bx = blockIdx.x;            // m tile 0..63
    int by = blockIdx.y;            // 0..23
    int mat = by / 6;
    int n0  = (by % 6) * 128;
    int m0  = bx * 128;
    const u16* Wh = wmats + (size_t)mat * 2 * WSZ;
    const u16* Wl = Wh + WSZ;
    const float* bias = (mat == 0) ? bq : (mat == 1) ? bk : (mat == 2) ? bv : bg;
    bool full = (mat == 2);

    __shared__ u16 Ah[4096], Al[4096], Bh[4096], Bl[4096];   // 32 KB

    int tid  = threadIdx.x;
    int lane = tid & 63, wid = tid >> 6;
    int wm = (wid & 1) * 64, wn = (wid >> 1) * 64;
    int fr = lane & 15, rq = (lane >> 4) * 4;

    f32x4 acc[4][4];
    #pragma unroll
    for (int i = 0; i < 4; ++i)
        #pragma unroll
        for (int j = 0; j < 4; ++j)
            acc[i][j] = (f32x4){0.f, 0.f, 0.f, 0.f};

    int j = tid >> 5, u = tid & 31;
    size_t offA = (size_t)(m0 + j * 16 + (u & 15)) * 768 + (u >> 4) * 8;
    size_t offB = (size_t)(n0 + j * 16 + (u & 15)) * 768 + (u >> 4) * 8;
    int lo0 = j * 512 + u * 8;      // u16 units
    int ba = (wm >> 4), bb2 = (wn >> 4);

    for (int k0 = 0; k0 < 768; k0 += 32) {
        // global loads (no LDS touch; previous iter's trailing compute still
        // running in other waves -- TLP covers the latency)
        uint4 a0 = *(const uint4*)(xh + offA + k0);
        uint4 a1 = *(const uint4*)(xh + offA + k0 + 16);
        uint4 c0 = *(const uint4*)(Wh + offB + k0);
        uint4 c1 = *(const uint4*)(Wh + offB + k0 + 16);
        uint4 b0, b1, d0, d1;
        if (full) {
            b0 = *(const uint4*)(xl + offA + k0);
            b1 = *(const uint4*)(xl + offA + k0 + 16);
            d0 = *(const uint4*)(Wl + offB + k0);
            d1 = *(const uint4*)(Wl + offB + k0 + 16);
        }
        __syncthreads();            // prior iter's LDS reads complete
        *(uint4*)(Ah + lo0) = a0;  *(uint4*)(Ah + lo0 + 256) = a1;
        *(uint4*)(Bh + lo0) = c0;  *(uint4*)(Bh + lo0 + 256) = c1;
        if (full) {
            *(uint4*)(Al + lo0) = b0;  *(uint4*)(Al + lo0 + 256) = b1;
            *(uint4*)(Bl + lo0) = d0;  *(uint4*)(Bl + lo0 + 256) = d1;
        }
        __syncthreads();            // staged and visible
        bf16x8 fah[4], fbh[4];
        #pragma unroll
        for (int i = 0; i < 4; ++i) {
            fah[i] = *(const bf16x8*)(Ah + (ba + i) * 512 + lane * 8);
            fbh[i] = *(const bf16x8*)(Bh + (bb2 + i) * 512 + lane * 8);
        }
        if (mat == 2) {
            bf16x8 fal[4], fbl[4];
            #pragma unroll
            for (int i = 0; i < 4; ++i) {
                fal[i] = *(const bf16x8*)(Al + (ba + i) * 512 + lane * 8);
                fbl[i] = *(const bf16x8*)(Bl + (bb2 + i) * 512 + lane * 8);
            }
            #pragma unroll
            for (int mi = 0; mi < 4; ++mi)
                #pragma unroll
                for (int ni = 0; ni < 4; ++ni) {
                    acc[mi][ni] = __builtin_amdgcn_mfma_f32_16x16x32_bf16(fbh[ni], fah[mi], acc[mi][ni], 0, 0, 0);
                    acc[mi][ni] = __builtin_amdgcn_mfma_f32_16x16x32_bf16(fbh[ni], fal[mi], acc[mi][ni], 0, 0, 0);
                    acc[mi][ni] = __builtin_amdgcn_mfma_f32_16x16x32_bf16(fbl[ni], fah[mi], acc[mi][ni], 0, 0, 0);
                }
        } else {   // q / k / gate: plain bf16, 1 MFMA
            #pragma unroll
            for (int mi = 0; mi < 4; ++mi)
                #pragma unroll
                for (int ni = 0; ni < 4; ++ni)
                    acc[mi][ni] = __builtin_amdgcn_mfma_f32_16x16x32_bf16(fah[mi], fbh[ni], acc[mi][ni], 0, 0, 0);
        }
    }
    // epilogue: C/D layout col=lane&15, row=(lane>>4)*4+reg; plain bf16 out
    if (mat == 2) {
        int bb = m0 >> 10;
        #pragma unroll
        for (int mi = 0; mi < 4; ++mi) {
            int tok = m0 + wm + mi * 16 + fr;
            int tl  = tok & 1023;
            #pragma unroll
            for (int ni = 0; ni < 4; ++ni) {
                #pragma unroll
                for (int rg = 0; rg < 4; ++rg) {
                    int ch = n0 + wn + ni * 16 + rq + rg;
                    float val = acc[mi][ni][rg] + bias[ch];
                    size_t addr = ((size_t)((bb * 12 + (ch >> 6)) * 64 + (ch & 63))) * 1024 + tl;
                    vth[addr] = bf16_hi(val);
                }
            }
        }
    } else {
        u16* oh = (mat == 0) ? qh : (mat == 1) ? kh : g;
        float scale = (mat == 0) ? 0.125f : 1.0f;
        #pragma unroll
        for (int ni = 0; ni < 4; ++ni) {
            int col = n0 + wn + ni * 16 + fr;
            float bb = bias[col];
            #pragma unroll
            for (int mi = 0; mi < 4; ++mi) {
                int row = m0 + wm + mi * 16 + rq;
                #pragma unroll
                for (int rg = 0; rg < 4; ++rg) {
                    float val = (acc[mi][ni][rg] + bb) * scale;
                    oh[(size_t)(row + rg) * 768 + col] = bf16_hi(val);
                }
            }
        }
    }
}

// ---------------------------------------------------------------------------
// Kernel 3: MFMA flash attention, plain-bf16 q/k/v. 8 QK + 8 PV MFMA per
// wave-stage. Single-barrier LDS double-buffer, 2-stage register prefetch.
// P via wave-private LDS strip (no barrier needed). (unchanged from R8)
// ---------------------------------------------------------------------------
__global__ __launch_bounds__(256, 3) void attn_mfma(
    const u16* __restrict__ qhg, const u16* __restrict__ khg,
    const u16* __restrict__ vthg, const u16* __restrict__ gbf,
    u16* __restrict__ yh, u16* __restrict__ yl) {
    int qt = blockIdx.x;   // 0..15
    int h  = blockIdx.y;   // 0..11
    int b  = blockIdx.z;   // 0..7
    __shared__ u16 Kh[2 * 4096], Vh[2 * 4096];
    __shared__ u16 Ps[64 * 72];
    int tid = threadIdx.x;
    int lane = tid & 63, w = tid >> 6;
    int fr = lane & 15, quad = lane >> 4, fq = quad * 8;

    size_t qbase = ((size_t)(b * 1024 + qt * 64)) * 768 + h * 64;
    size_t kbase = ((size_t)(b * 1024)) * 768 + h * 64;
    size_t vbase = ((size_t)((b * 12 + h) * 64)) * 1024;

    // Q A-fragments direct from global (loop-invariant, pre-scaled 1/8)
    bf16x8 aq[2];
    #pragma unroll
    for (int kk = 0; kk < 2; ++kk)
        aq[kk] = *(const bf16x8*)(qhg + qbase + (size_t)(w * 16 + fr) * 768 + kk * 32 + fq);

    float m_i[4], l_i[4];
    f32x4 Oacc[4];
    #pragma unroll
    for (int i = 0; i < 4; ++i) {
        m_i[i] = -1e30f; l_i[i] = 0.0f;
        Oacc[i] = (f32x4){0.f, 0.f, 0.f, 0.f};
    }

    int j = tid >> 5, u = tid & 31;
    int kk_ = j >> 2, nd_ = j & 3;
    size_t offK = kbase + (size_t)(nd_ * 16 + (u & 15)) * 768 + kk_ * 32 + (u >> 4) * 8;
    size_t offV = vbase + (size_t)(nd_ * 16 + (u & 15)) * 1024 + kk_ * 32 + (u >> 4) * 8;
    int lo0 = j * 512 + u * 8;

    uint4 rk0, rk1, rv0, rv1;
    #define LOADKV(ST) do { \
        size_t ok = offK + (size_t)(ST) * 49152; \
        size_t ov = offV + (size_t)(ST) * 64; \
        rk0 = *(const uint4*)(khg + ok);  rk1 = *(const uint4*)(khg + ok + 16); \
        rv0 = *(const uint4*)(vthg + ov); rv1 = *(const uint4*)(vthg + ov + 16); \
    } while (0)
    #define STOREKV(BUF) do { \
        int lb = (BUF) * 4096 + lo0; \
        *(uint4*)(Kh + lb) = rk0;  *(uint4*)(Kh + lb + 256) = rk1; \
        *(uint4*)(Vh + lb) = rv0;  *(uint4*)(Vh + lb + 256) = rv1; \
    } while (0)

    LOADKV(0);
    STOREKV(0);
    LOADKV(1);
    __syncthreads();
    int cur = 0;
    for (int st = 0; st < 16; ++st) {
        int nxt = cur ^ 1;
        STOREKV(nxt);                  // stage st+1 (garbage on last, never read)
        int s2 = (st + 2 < 16) ? (st + 2) : 0;
        LOADKV(s2);
        // S = Q K^T (wave strip 16 x 64)
        f32x4 sacc[4];
        #pragma unroll
        for (int nt = 0; nt < 4; ++nt) sacc[nt] = (f32x4){0.f, 0.f, 0.f, 0.f};
        #pragma unroll
        for (int nt = 0; nt < 4; ++nt)
            #pragma unroll
            for (int kk = 0; kk < 2; ++kk) {
                bf16x8 kb = *(const bf16x8*)(Kh + cur * 4096 + (kk * 4 + nt) * 512 + lane * 8);
                sacc[nt] = __builtin_amdgcn_mfma_f32_16x16x32_bf16(aq[kk], kb, sacc[nt], 0, 0, 0);
            }
        // online softmax per owned row (row = w*16 + quad*4 + rg)
        #pragma unroll
        for (int rg = 0; rg < 4; ++rg) {
            float mx = fmaxf(fmaxf(sacc[0][rg], sacc[1][rg]),
                             fmaxf(sacc[2][rg], sacc[3][rg]));
            #pragma unroll
            for (int msk = 1; msk < 16; msk <<= 1) mx = fmaxf(mx, __shfl_xor(mx, msk));
            float mn = fmaxf(m_i[rg], mx);
            float al = __expf(m_i[rg] - mn);
            float p0 = __expf(sacc[0][rg] - mn);
            float p1 = __expf(sacc[1][rg] - mn);
            float p2 = __expf(sacc[2][rg] - mn);
            float p3 = __expf(sacc[3][rg] - mn);
            float rs = p0 + p1 + p2 + p3;
            #pragma unroll
            for (int msk = 1; msk < 16; msk <<= 1) rs += __shfl_xor(rs, msk);
            l_i[rg] = l_i[rg] * al + rs;
            m_i[rg] = mn;
            #pragma unroll
            for (int dn = 0; dn < 4; ++dn) Oacc[dn][rg] *= al;
            int row = w * 16 + quad * 4 + rg;
            Ps[row * 72 +  0 + fr] = bf16_hi(p0);
            Ps[row * 72 + 16 + fr] = bf16_hi(p1);
            Ps[row * 72 + 32 + fr] = bf16_hi(p2);
            Ps[row * 72 + 48 + fr] = bf16_hi(p3);
        }
        // O += P V (P wave-private rows; V in buf[cur])
        #pragma unroll
        for (int kk = 0; kk < 2; ++kk) {
            bf16x8 pa = *(const bf16x8*)&Ps[(w * 16 + fr) * 72 + fq + kk * 32];
            #pragma unroll
            for (int dn = 0; dn < 4; ++dn) {
                bf16x8 vb = *(const bf16x8*)(Vh + cur * 4096 + (kk * 4 + dn) * 512 + lane * 8);
                Oacc[dn] = __builtin_amdgcn_mfma_f32_16x16x32_bf16(pa, vb, Oacc[dn], 0, 0, 0);
            }
        }
        __syncthreads();
        cur = nxt;
    }
    #undef LOADKV
    #undef STOREKV
    // epilogue: normalize, sigmoid gate, split-store y
    float inv[4];
    #pragma unroll
    for (int rg = 0; rg < 4; ++rg) inv[rg] = 1.0f / l_i[rg];
    #pragma unroll
    for (int dn = 0; dn < 4; ++dn) {
        int ch = h * 64 + dn * 16 + fr;
        #pragma unroll
        for (int rg = 0; rg < 4; ++rg) {
            int tok = b * 1024 + qt * 64 + w * 16 + quad * 4 + rg;
            float gv = bf16_f(gbf[(size_t)tok * 768 + ch]);
            float sg = 1.0f / (1.0f + __expf(-gv));
            float val = Oacc[dn][rg] * inv[rg] * sg;
            u16 hh, ll;
            split_bf16(val, hh, ll);
            yh[(size_t)tok * 768 + ch] = hh;
            yl[(size_t)tok * 768 + ch] = ll;
        }
    }
}

// ---------------------------------------------------------------------------
// Kernel 4: out = y @ Wo^T + bo -> (B, C, T), split-bf16 16x16x32 MFMA.
// Simple 2-barrier single-buffer (32 KB -> 4 blocks/CU), fragment-ordered LDS.
// Split kept: Wo/y errors land directly on the output.
// ---------------------------------------------------------------------------
__global__ __launch_bounds__(256, 2) void out_mfma(
    const u16* __restrict__ yh, const u16* __restrict__ yl,
    const u16* __restrict__ woh, const u16* __restrict__ wol,
    const float* __restrict__ bo, float* __restrict__ out) {
    int bx = blockIdx.x;   // c tile 0..5
    int by = blockIdx.y;   // t tile 0..63
    int m0 = bx * 128;     // c
    int n0 = by * 128;     // t

    __shared__ u16 Ah[4096], Al[4096], Bh[4096], Bl[4096];   // 32 KB

    int tid  = threadIdx.x;
    int lane = tid & 63, wid = tid >> 6;
    int wm = (wid & 1) * 64, wn = (wid >> 1) * 64;
    int fr = lane & 15, rq = (lane >> 4) * 4;

    f32x4 acc[4][4];
    #pragma unroll
    for (int i = 0; i < 4; ++i)
        #pragma unroll
        for (int j = 0; j < 4; ++j)
            acc[i][j] = (f32x4){0.f, 0.f, 0.f, 0.f};

    int j = tid >> 5, u = tid & 31;
    size_t offA = (size_t)(m0 + j * 16 + (u & 15)) * 768 + (u >> 4) * 8;
    size_t offB = (size_t)(n0 + j * 16 + (u & 15)) * 768 + (u >> 4) * 8;
    int lo0 = j * 512 + u * 8;
    int ba = (wm >> 4), bb2 = (wn >> 4);

    for (int k0 = 0; k0 < 768; k0 += 32) {
        uint4 a0 = *(const uint4*)(woh + offA + k0);
        uint4 a1 = *(const uint4*)(woh + offA + k0 + 16);
        uint4 b0 = *(const uint4*)(wol + offA + k0);
        uint4 b1 = *(const uint4*)(wol + offA + k0 + 16);
        uint4 c0 = *(const uint4*)(yh + offB + k0);
        uint4 c1 = *(const uint4*)(yh + offB + k0 + 16);
        uint4 d0 = *(const uint4*)(yl + offB + k0);
        uint4 d1 = *(const uint4*)(yl + offB + k0 + 16);
        __syncthreads();
        *(uint4*)(Ah + lo0) = a0;  *(uint4*)(Ah + lo0 + 256) = a1;
        *(uint4*)(Al + lo0) = b0;  *(uint4*)(Al + lo0 + 256) = b1;
        *(uint4*)(Bh + lo0) = c0;  *(uint4*)(Bh + lo0 + 256) = c1;
        *(uint4*)(Bl + lo0) = d0;  *(uint4*)(Bl + lo0 + 256) = d1;
        __syncthreads();
        bf16x8 fah[4], fal[4], fbh[4], fbl[4];
        #pragma unroll
        for (int i = 0; i < 4; ++i) {
            fah[i] = *(const bf16x8*)(Ah + (ba + i) * 512 + lane * 8);
            fal[i] = *(const bf16x8*)(Al + (ba + i) * 512 + lane * 8);
            fbh[i] = *(const bf16x8*)(Bh + (bb2 + i) * 512 + lane * 8);
            fbl[i] = *(const bf16x8*)(Bl + (bb2 + i) * 512 + lane * 8);
        }
        #pragma unroll
        for (int mi = 0; mi < 4; ++mi)
            #pragma unroll
            for (int ni = 0; ni < 4; ++ni) {
                acc[mi][ni] = __builtin_amdgcn_mfma_f32_16x16x32_bf16(fah[mi], fbh[ni], acc[mi][ni], 0, 0, 0);
                acc[mi][ni] = __builtin_amdgcn_mfma_f32_16x16x32_bf16(fah[mi], fbl[ni], acc[mi][ni], 0, 0, 0);
                acc[mi][ni] = __builtin_amdgcn_mfma_f32_16x16x32_bf16(fal[mi], fbh[ni], acc[mi][ni], 0, 0, 0);
            }
    }
    int bb = n0 >> 10;
    #pragma unroll
    for (int ni = 0; ni < 4; ++ni) {
        int colg = n0 + wn + ni * 16 + fr;
        int tl = colg & 1023;
        #pragma unroll
        for (int mi = 0; mi < 4; ++mi) {
            int row = m0 + wm + mi * 16 + rq;
            #pragma unroll
            for (int rg = 0; rg < 4; ++rg) {
                float val = acc[mi][ni][rg] + bo[row + rg];
                out[((size_t)bb * 768 + row + rg) * 1024 + tl] = val;
            }
        }
    }
}

extern "C" void kernel_launch(void* const* d_in, const int* in_sizes, int n_in,
                              void* d_out, int out_size, void* d_ws, size_t ws_size,
                              hipStream_t stream) {
    const float* x     = (const float*)d_in[0];
    const float* Wq    = (const float*)d_in[1];
    const float* bq    = (const float*)d_in[2];
    const float* Wk    = (const float*)d_in[3];
    const float* bk    = (const float*)d_in[4];
    const float* Wv    = (const float*)d_in[5];
    const float* bv    = (const float*)d_in[6];
    const float* Wo    = (const float*)d_in[7];
    const float* bo    = (const float*)d_in[8];
    const float* Wg    = (const float*)d_in[9];
    const float* bg    = (const float*)d_in[10];
    const float* gamma = (const float*)d_in[11];
    const float* beta  = (const float*)d_in[12];
    float* out = (float*)d_out;

    // workspace (ushort): xn_h|xn_l|qh|kh|vth|g | wbuf ; y aliases xn
    const size_t S = (size_t)BT_ * C_;
    u16* xn_hi = (u16*)d_ws;
    u16* xn_lo = xn_hi + S;
    u16* qh    = xn_lo + S;
    u16* kh    = qh + S;
    u16* vth   = kh + S;
    u16* g_bf  = vth + S;
    u16* wbuf  = g_bf + S;   // [Wq,Wk,Wv,Wg,Wo] x {hi,lo}
    u16* y_hi  = xn_hi;      // alias: xn dead after qkvg
    u16* y_lo  = xn_lo;

    wconv_all<<<dim3(WSZ / 1024, 5), 256, 0, stream>>>(Wq, Wk, Wv, Wg, Wo, wbuf);
    ln_kernel<<<BT_, 256, 0, stream>>>(x, gamma, beta, xn_hi, xn_lo);
    qkvg_mfma<<<dim3(64, 24), 256, 0, stream>>>(xn_hi, xn_lo, wbuf,
                                                bq, bk, bv, bg,
                                                qh, kh, vth, g_bf);
    attn_mfma<<<dim3(16, 12, 8), 256, 0, stream>>>(qh, kh, vth, g_bf,
                                                   y_hi, y_lo);
    out_mfma<<<dim3(6, 64), 256, 0, stream>>>(y_hi, y_lo,
                                              wbuf + (size_t)8 * WSZ,
                                              wbuf + (size_t)9 * WSZ, bo, out);
}